// Round 1
// baseline (3392.280 us; speedup 1.0000x reference)
//
#include <hip/hip_runtime.h>
#include <math.h>

static constexpr int KNN = 40;

__device__ __forceinline__ float lrelu_f(float v){ return v >= 0.f ? v : 0.5f*v; }

// ---------------- generic fused linear: Y = act(X@W + b [+ X2@W2]) ----------------
// Block: 64*CG threads; 64 rows per block; thread t -> row (t&63), col-group (t>>6)*16.
template<int K, int NOUT, bool RELU, bool DUAL>
__global__ __launch_bounds__(64*((NOUT+15)/16))
void lin_kernel(const float* __restrict__ X, const float* __restrict__ W,
                const float* __restrict__ Bv,
                const float* __restrict__ X2, const float* __restrict__ W2,
                float* __restrict__ Y, int ypitch)
{
    constexpr int NP = ((NOUT+15)/16)*16;
    constexpr int CG = NP/16;
    constexpr int NTH = 64*CG;
    constexpr int KP = (K % 2 == 0) ? (K+1) : K;   // odd LDS pitch -> conflict-free
    __shared__ __align__(16) float Xs[64*KP];
    __shared__ __align__(16) float Ws[K*NP];
    __shared__ __align__(16) float X2s[DUAL ? 64*KP : 4];
    __shared__ __align__(16) float W2s[DUAL ? K*NP : 4];
    __shared__ float Bs[NP];
    const int t  = threadIdx.x;
    const int r  = t & 63;
    const int cg = t >> 6;
    const long row0 = (long)blockIdx.x * 64;

    for (int i = t; i < K*NP; i += NTH) {
        int k = i / NP, c = i - k*NP;
        Ws[i] = (c < NOUT) ? W[k*NOUT + c] : 0.f;
        if (DUAL) W2s[i] = (c < NOUT) ? W2[k*NOUT + c] : 0.f;
    }
    for (int i = t; i < NP; i += NTH) Bs[i] = (i < NOUT) ? Bv[i] : 0.f;
    for (int i = t; i < 64*K; i += NTH) {
        int rr = i / K, cc = i - rr*K;
        Xs[rr*KP + cc] = X[(row0+rr)*K + cc];
        if (DUAL) X2s[rr*KP + cc] = X2[(row0+rr)*K + cc];
    }
    __syncthreads();

    float acc[16];
    #pragma unroll
    for (int j=0;j<16;++j) acc[j] = Bs[cg*16+j];

    {
        const float* xrow = &Xs[r*KP];
        #pragma unroll 4
        for (int k=0;k<K;++k) {
            float xv = xrow[k];
            const float4* wp = reinterpret_cast<const float4*>(&Ws[k*NP + cg*16]);
            float4 w0 = wp[0], w1 = wp[1], w2 = wp[2], w3 = wp[3];
            acc[0] = fmaf(xv,w0.x,acc[0]);  acc[1] = fmaf(xv,w0.y,acc[1]);
            acc[2] = fmaf(xv,w0.z,acc[2]);  acc[3] = fmaf(xv,w0.w,acc[3]);
            acc[4] = fmaf(xv,w1.x,acc[4]);  acc[5] = fmaf(xv,w1.y,acc[5]);
            acc[6] = fmaf(xv,w1.z,acc[6]);  acc[7] = fmaf(xv,w1.w,acc[7]);
            acc[8] = fmaf(xv,w2.x,acc[8]);  acc[9] = fmaf(xv,w2.y,acc[9]);
            acc[10]= fmaf(xv,w2.z,acc[10]); acc[11]= fmaf(xv,w2.w,acc[11]);
            acc[12]= fmaf(xv,w3.x,acc[12]); acc[13]= fmaf(xv,w3.y,acc[13]);
            acc[14]= fmaf(xv,w3.z,acc[14]); acc[15]= fmaf(xv,w3.w,acc[15]);
        }
    }
    if (DUAL) {
        const float* xrow = &X2s[r*KP];
        #pragma unroll 4
        for (int k=0;k<K;++k) {
            float xv = xrow[k];
            const float4* wp = reinterpret_cast<const float4*>(&W2s[k*NP + cg*16]);
            float4 w0 = wp[0], w1 = wp[1], w2 = wp[2], w3 = wp[3];
            acc[0] = fmaf(xv,w0.x,acc[0]);  acc[1] = fmaf(xv,w0.y,acc[1]);
            acc[2] = fmaf(xv,w0.z,acc[2]);  acc[3] = fmaf(xv,w0.w,acc[3]);
            acc[4] = fmaf(xv,w1.x,acc[4]);  acc[5] = fmaf(xv,w1.y,acc[5]);
            acc[6] = fmaf(xv,w1.z,acc[6]);  acc[7] = fmaf(xv,w1.w,acc[7]);
            acc[8] = fmaf(xv,w2.x,acc[8]);  acc[9] = fmaf(xv,w2.y,acc[9]);
            acc[10]= fmaf(xv,w2.z,acc[10]); acc[11]= fmaf(xv,w2.w,acc[11]);
            acc[12]= fmaf(xv,w3.x,acc[12]); acc[13]= fmaf(xv,w3.y,acc[13]);
            acc[14]= fmaf(xv,w3.z,acc[14]); acc[15]= fmaf(xv,w3.w,acc[15]);
        }
    }
    #pragma unroll
    for (int j=0;j<16;++j) {
        int c = cg*16 + j;
        if (c < NOUT) {
            float v = acc[j];
            if (RELU) v = lrelu_f(v);
            Y[(row0+r)*ypitch + c] = v;
        }
    }
}

// ---------------- |s|^2 ----------------
__global__ void sq_kernel(const float* __restrict__ S, float* __restrict__ SQ)
{
    int i = blockIdx.x*blockDim.x + threadIdx.x;
    const float4* sp = reinterpret_cast<const float4*>(&S[(long)i*8]);
    float4 a = sp[0], b = sp[1];
    SQ[i] = a.x*a.x + a.y*a.y + a.z*a.z + a.w*a.w
          + b.x*b.x + b.y*b.y + b.z*b.z + b.w*b.w;
}

// ---------------- brute-force kNN (K=40) ----------------
// Block: 256 threads = 4 waves; block owns 64 queries; wave w scans candidate
// quarter [w*N/4,(w+1)*N/4); per-thread 40-entry max-heap in LDS; wave 0 merges.
__device__ __forceinline__ void heap_sift(float* myd, int* myi, float d, int j)
{
    int p = 0;
    while (true) {
        int c1 = 2*p + 1;
        if (c1 >= KNN) break;
        float cd = myd[c1]; int ci = c1;
        int c2 = c1 + 1;
        if (c2 < KNN) { float cd2 = myd[c2]; if (cd2 > cd) { cd = cd2; ci = c2; } }
        if (cd <= d) break;
        myd[p] = cd; myi[p] = myi[ci];
        p = ci;
    }
    myd[p] = d; myi[p] = j;
}

__global__ __launch_bounds__(256)
void knn_kernel(const float* __restrict__ S, const float* __restrict__ SQ,
                int* __restrict__ idx_out, float* __restrict__ w_out, int N)
{
    __shared__ float hd[256*KNN];
    __shared__ int   hi[256*KNN];
    __shared__ __align__(16) float tile[4][64][9];
    const int t    = threadIdx.x;
    const int lane = t & 63;
    const int wv   = t >> 6;
    const int q    = blockIdx.x*64 + lane;
    const float4* sp = reinterpret_cast<const float4*>(&S[(long)q*8]);
    const float4 sa = sp[0], sb = sp[1];
    const float sqi = SQ[q];
    float* myd = &hd[t*KNN];
    int*   myi = &hi[t*KNN];
    #pragma unroll
    for (int p=0;p<KNN;++p){ myd[p] = INFINITY; myi[p] = -1; }
    float root = INFINITY;
    const int chunk = N >> 2;
    const int cbase = wv * chunk;
    for (int t0 = 0; t0 < chunk; t0 += 64) {
        __syncthreads();
        {
            int c = cbase + t0 + lane;
            const float4* cp = reinterpret_cast<const float4*>(&S[(long)c*8]);
            float4 ca = cp[0], cb = cp[1];
            float* tl = tile[wv][lane];
            tl[0]=ca.x; tl[1]=ca.y; tl[2]=ca.z; tl[3]=ca.w;
            tl[4]=cb.x; tl[5]=cb.y; tl[6]=cb.z; tl[7]=cb.w;
            tl[8]=SQ[c];
        }
        __syncthreads();
        #pragma unroll 1
        for (int u=0; u<64; ++u) {
            const float* tl = tile[wv][u];
            float dot = sa.x*tl[0] + sa.y*tl[1] + sa.z*tl[2] + sa.w*tl[3]
                      + sb.x*tl[4] + sb.y*tl[5] + sb.z*tl[6] + sb.w*tl[7];
            float d2 = sqi + tl[8] - 2.f*dot;
            int j = cbase + t0 + u;
            if (d2 < root && j != q) {
                heap_sift(myd, myi, d2, j);
                root = myd[0];
            }
        }
    }
    __syncthreads();
    if (t < 64) {
        for (int w2 = 1; w2 < 4; ++w2) {
            const float* od = &hd[(w2*64+lane)*KNN];
            const int*   oi = &hi[(w2*64+lane)*KNN];
            for (int p2 = 0; p2 < KNN; ++p2) {
                float d = od[p2];
                if (d < root) {
                    heap_sift(myd, myi, d, oi[p2]);
                    root = myd[0];
                }
            }
        }
        #pragma unroll 1
        for (int p = 0; p < KNN; ++p) {
            idx_out[(long)q*KNN + p] = myi[p];
            w_out[(long)q*KNN + p]   = expf(-10.f * myd[p]);
        }
    }
}

// ---------------- GravNet aggregate: [mean(h*w), max(h*w), x12] -> 56 ----------------
__global__ void gravnet_agg(const float* __restrict__ H /*pitch 24*/,
                            const int* __restrict__ idx, const float* __restrict__ wgt,
                            const float* __restrict__ X12, float* __restrict__ OUT /*pitch 56*/)
{
    int n = blockIdx.x*blockDim.x + threadIdx.x;
    float sum[22], mx[22];
    #pragma unroll
    for (int f=0;f<22;++f){ sum[f]=0.f; mx[f]=-INFINITY; }
    #pragma unroll 1
    for (int k=0;k<KNN;++k) {
        int j = idx[(long)n*KNN+k];
        float wv = wgt[(long)n*KNN+k];
        const float4* hp = reinterpret_cast<const float4*>(&H[(long)j*24]);
        float4 h0=hp[0],h1=hp[1],h2=hp[2],h3=hp[3],h4=hp[4],h5=hp[5];
        float hv[24] = {h0.x,h0.y,h0.z,h0.w, h1.x,h1.y,h1.z,h1.w,
                        h2.x,h2.y,h2.z,h2.w, h3.x,h3.y,h3.z,h3.w,
                        h4.x,h4.y,h4.z,h4.w, h5.x,h5.y,h5.z,h5.w};
        #pragma unroll
        for (int f=0;f<22;++f){ float m = hv[f]*wv; sum[f]+=m; mx[f]=fmaxf(mx[f],m); }
    }
    float* o = &OUT[(long)n*56];
    #pragma unroll
    for (int f=0;f<22;++f){ o[f] = sum[f]*(1.f/40.f); o[22+f] = mx[f]; }
    const float* xp = &X12[(long)n*12];
    #pragma unroll
    for (int d=0;d<12;++d) o[44+d] = xp[d];
}

// ---------------- GraphConv neighbor sum: sum_k xg[idx_k]*w_k ----------------
__global__ void graphconv_gather(const float* __restrict__ XG, const int* __restrict__ idx,
                                 const float* __restrict__ wgt, float* __restrict__ OUT)
{
    int n = blockIdx.x*blockDim.x + threadIdx.x;
    float acc[64];
    #pragma unroll
    for (int c=0;c<64;++c) acc[c]=0.f;
    #pragma unroll 1
    for (int k=0;k<KNN;++k) {
        int j = idx[(long)n*KNN+k];
        float wv = wgt[(long)n*KNN+k];
        const float4* xp = reinterpret_cast<const float4*>(&XG[(long)j*64]);
        #pragma unroll
        for (int c=0;c<16;++c) {
            float4 v = xp[c];
            acc[4*c+0] = fmaf(v.x,wv,acc[4*c+0]);
            acc[4*c+1] = fmaf(v.y,wv,acc[4*c+1]);
            acc[4*c+2] = fmaf(v.z,wv,acc[4*c+2]);
            acc[4*c+3] = fmaf(v.w,wv,acc[4*c+3]);
        }
    }
    float4* op = reinterpret_cast<float4*>(&OUT[(long)n*64]);
    #pragma unroll
    for (int c=0;c<16;++c) op[c] = make_float4(acc[4*c],acc[4*c+1],acc[4*c+2],acc[4*c+3]);
}

// ---------------- concat [xc(64), cand_ids(6), x0(12)] -> 82 ----------------
__global__ void cat82_kernel(const float* __restrict__ xc, const float* __restrict__ ids,
                             const float* __restrict__ x0, float* __restrict__ Z)
{
    int n = blockIdx.x*blockDim.x + threadIdx.x;
    float* z = &Z[(long)n*82];
    const float* a = &xc[(long)n*64];
    #pragma unroll 8
    for (int c=0;c<64;++c) z[c] = a[c];
    const float* b = &ids[(long)n*6];
    #pragma unroll
    for (int j=0;j<6;++j) z[64+j] = b[j];
    const float* d = &x0[(long)n*12];
    #pragma unroll
    for (int j=0;j<12;++j) z[70+j] = d[j];
}

// ---------------- passthrough outputs ----------------
__global__ void copyout_kernel(const int* __restrict__ gid, const float* __restrict__ gy,
                               const int* __restrict__ cid, const float* __restrict__ cy,
                               float* __restrict__ out, int N)
{
    long i = (long)blockIdx.x*blockDim.x + threadIdx.x;
    long n = N;
    if (i < n)            out[12*n + i]         = (float)gid[i];
    else if (i < 7*n)     out[13*n + (i - n)]   = gy[i - n];
    else if (i < 8*n)     out[19*n + (i - 7*n)] = (float)cid[i - 7*n];
    else if (i < 14*n)    out[20*n + (i - 8*n)] = cy[i - 8*n];
}

extern "C" void kernel_launch(void* const* d_in, const int* in_sizes, int n_in,
                              void* d_out, int out_size, void* d_ws, size_t ws_size,
                              hipStream_t stream)
{
    const float* x0     = (const float*)d_in[0];
    const float* ygen   = (const float*)d_in[1];
    const float* ycand  = (const float*)d_in[2];
    const int*   ygenid = (const int*)d_in[3];
    const int*   ycandid= (const int*)d_in[4];
    const float* n1W0=(const float*)d_in[5],  *n1b0=(const float*)d_in[6];
    const float* n1W1=(const float*)d_in[7],  *n1b1=(const float*)d_in[8];
    const float* n1W2=(const float*)d_in[9],  *n1b2=(const float*)d_in[10];
    const float* gWs =(const float*)d_in[11], *gbs =(const float*)d_in[12];
    const float* gWh =(const float*)d_in[13], *gbh =(const float*)d_in[14];
    const float* gWo =(const float*)d_in[15], *gbo =(const float*)d_in[16];
    const float* c2Wrel=(const float*)d_in[17], *c2brel=(const float*)d_in[18];
    const float* c2Wroot=(const float*)d_in[19];
    const float* n2W0=(const float*)d_in[20], *n2b0=(const float*)d_in[21];
    const float* n2W1=(const float*)d_in[22], *n2b1=(const float*)d_in[23];
    const float* n2W2=(const float*)d_in[24], *n2b2=(const float*)d_in[25];
    const float* n2W3=(const float*)d_in[26], *n2b3=(const float*)d_in[27];
    const float* n3W0=(const float*)d_in[28], *n3b0=(const float*)d_in[29];
    const float* n3W1=(const float*)d_in[30], *n3b1=(const float*)d_in[31];
    const float* n3W2=(const float*)d_in[32], *n3b2=(const float*)d_in[33];
    const float* n3W3=(const float*)d_in[34], *n3b3=(const float*)d_in[35];

    const int N = in_sizes[0] / 12;      // 16384
    float* ws = (float*)d_ws;
    size_t off = 0;
    auto alloc = [&](size_t cnt){ float* p = ws + off; off += cnt; return p; };
    float* A    = alloc((size_t)N*128);
    float* Bb   = alloc((size_t)N*128);
    float* x12  = alloc((size_t)N*12);
    float* s    = alloc((size_t)N*8);
    float* sq   = alloc((size_t)N);
    float* h    = alloc((size_t)N*24);
    int*   idxb = (int*)alloc((size_t)N*KNN);
    float* wb   = alloc((size_t)N*KNN);
    float* xg   = alloc((size_t)N*64);
    float* xc   = alloc((size_t)N*64);
    (void)ws_size; (void)n_in; (void)out_size;

    float* outF = (float*)d_out;
    const int GB = N / 64;               // 256 blocks

    // nn1 encoder
    lin_kernel<12,64,true,false><<<GB,256,0,stream>>>(x0,  n1W0, n1b0, nullptr, nullptr, A,   64);
    lin_kernel<64,64,true,false><<<GB,256,0,stream>>>(A,   n1W1, n1b1, nullptr, nullptr, Bb,  64);
    lin_kernel<64,12,true,false><<<GB, 64,0,stream>>>(Bb,  n1W2, n1b2, nullptr, nullptr, x12, 12);
    // GravNet space/feature projections
    lin_kernel<12, 8,false,false><<<GB, 64,0,stream>>>(x12, gWs, gbs, nullptr, nullptr, s, 8);
    lin_kernel<12,22,false,false><<<GB,128,0,stream>>>(x12, gWh, gbh, nullptr, nullptr, h, 24);
    sq_kernel<<<N/256,256,0,stream>>>(s, sq);
    knn_kernel<<<GB,256,0,stream>>>(s, sq, idxb, wb, N);
    gravnet_agg<<<GB,64,0,stream>>>(h, idxb, wb, x12, A);
    lin_kernel<56,64,false,false><<<GB,256,0,stream>>>(A, gWo, gbo, nullptr, nullptr, xg, 64);
    // GraphConv
    graphconv_gather<<<GB,64,0,stream>>>(xg, idxb, wb, Bb);
    lin_kernel<64,64,false,true><<<GB,256,0,stream>>>(Bb, c2Wrel, c2brel, xg, c2Wroot, xc, 64);
    // nn2 head -> cand_ids at d_out[0:6N]
    lin_kernel<64,126,true,false><<<GB,512,0,stream>>>(xc, n2W0, n2b0, nullptr, nullptr, A, 126);
    lin_kernel<126,126,true,false><<<GB,512,0,stream>>>(A,  n2W1, n2b1, nullptr, nullptr, Bb,126);
    lin_kernel<126,126,true,false><<<GB,512,0,stream>>>(Bb, n2W2, n2b2, nullptr, nullptr, A, 126);
    lin_kernel<126,6,true,false><<<GB, 64,0,stream>>>(A,  n2W3, n2b3, nullptr, nullptr, outF, 6);
    // nn3 head -> cand_p4 at d_out[6N:12N]
    cat82_kernel<<<N/256,256,0,stream>>>(xc, outF, x0, Bb);
    lin_kernel<82,126,true,false><<<GB,512,0,stream>>>(Bb, n3W0, n3b0, nullptr, nullptr, A, 126);
    lin_kernel<126,126,true,false><<<GB,512,0,stream>>>(A,  n3W1, n3b1, nullptr, nullptr, Bb,126);
    lin_kernel<126,126,true,false><<<GB,512,0,stream>>>(Bb, n3W2, n3b2, nullptr, nullptr, A, 126);
    lin_kernel<126,6,true,false><<<GB, 64,0,stream>>>(A,  n3W3, n3b3, nullptr, nullptr, outF + (size_t)N*6, 6);
    // passthrough outputs
    copyout_kernel<<<(14*N+255)/256,256,0,stream>>>(ygenid, ygen, ycandid, ycand, outF, N);
}

// Round 3
// 1144.720 us; speedup vs baseline: 2.9634x; 2.9634x over previous
//
#include <hip/hip_runtime.h>
#include <math.h>

static constexpr int KNN = 40;

__device__ __forceinline__ float lrelu_f(float v){ return v >= 0.f ? v : 0.5f*v; }

// ---------------- generic fused linear: Y = act(X@W + b [+ X2@W2]) ----------------
template<int K, int NOUT, bool RELU, bool DUAL>
__global__ __launch_bounds__(64*((NOUT+15)/16))
void lin_kernel(const float* __restrict__ X, const float* __restrict__ W,
                const float* __restrict__ Bv,
                const float* __restrict__ X2, const float* __restrict__ W2,
                float* __restrict__ Y, int ypitch)
{
    constexpr int NP = ((NOUT+15)/16)*16;
    constexpr int CG = NP/16;
    constexpr int NTH = 64*CG;
    constexpr int KP = (K % 2 == 0) ? (K+1) : K;
    __shared__ __align__(16) float Xs[64*KP];
    __shared__ __align__(16) float Ws[K*NP];
    __shared__ __align__(16) float X2s[DUAL ? 64*KP : 4];
    __shared__ __align__(16) float W2s[DUAL ? K*NP : 4];
    __shared__ float Bs[NP];
    const int t  = threadIdx.x;
    const int r  = t & 63;
    const int cg = t >> 6;
    const long row0 = (long)blockIdx.x * 64;

    for (int i = t; i < K*NP; i += NTH) {
        int k = i / NP, c = i - k*NP;
        Ws[i] = (c < NOUT) ? W[k*NOUT + c] : 0.f;
        if (DUAL) W2s[i] = (c < NOUT) ? W2[k*NOUT + c] : 0.f;
    }
    for (int i = t; i < NP; i += NTH) Bs[i] = (i < NOUT) ? Bv[i] : 0.f;
    for (int i = t; i < 64*K; i += NTH) {
        int rr = i / K, cc = i - rr*K;
        Xs[rr*KP + cc] = X[(row0+rr)*K + cc];
        if (DUAL) X2s[rr*KP + cc] = X2[(row0+rr)*K + cc];
    }
    __syncthreads();

    float acc[16];
    #pragma unroll
    for (int j=0;j<16;++j) acc[j] = Bs[cg*16+j];

    {
        const float* xrow = &Xs[r*KP];
        #pragma unroll 4
        for (int k=0;k<K;++k) {
            float xv = xrow[k];
            const float4* wp = reinterpret_cast<const float4*>(&Ws[k*NP + cg*16]);
            float4 w0 = wp[0], w1 = wp[1], w2 = wp[2], w3 = wp[3];
            acc[0] = fmaf(xv,w0.x,acc[0]);  acc[1] = fmaf(xv,w0.y,acc[1]);
            acc[2] = fmaf(xv,w0.z,acc[2]);  acc[3] = fmaf(xv,w0.w,acc[3]);
            acc[4] = fmaf(xv,w1.x,acc[4]);  acc[5] = fmaf(xv,w1.y,acc[5]);
            acc[6] = fmaf(xv,w1.z,acc[6]);  acc[7] = fmaf(xv,w1.w,acc[7]);
            acc[8] = fmaf(xv,w2.x,acc[8]);  acc[9] = fmaf(xv,w2.y,acc[9]);
            acc[10]= fmaf(xv,w2.z,acc[10]); acc[11]= fmaf(xv,w2.w,acc[11]);
            acc[12]= fmaf(xv,w3.x,acc[12]); acc[13]= fmaf(xv,w3.y,acc[13]);
            acc[14]= fmaf(xv,w3.z,acc[14]); acc[15]= fmaf(xv,w3.w,acc[15]);
        }
    }
    if (DUAL) {
        const float* xrow = &X2s[r*KP];
        #pragma unroll 4
        for (int k=0;k<K;++k) {
            float xv = xrow[k];
            const float4* wp = reinterpret_cast<const float4*>(&W2s[k*NP + cg*16]);
            float4 w0 = wp[0], w1 = wp[1], w2 = wp[2], w3 = wp[3];
            acc[0] = fmaf(xv,w0.x,acc[0]);  acc[1] = fmaf(xv,w0.y,acc[1]);
            acc[2] = fmaf(xv,w0.z,acc[2]);  acc[3] = fmaf(xv,w0.w,acc[3]);
            acc[4] = fmaf(xv,w1.x,acc[4]);  acc[5] = fmaf(xv,w1.y,acc[5]);
            acc[6] = fmaf(xv,w1.z,acc[6]);  acc[7] = fmaf(xv,w1.w,acc[7]);
            acc[8] = fmaf(xv,w2.x,acc[8]);  acc[9] = fmaf(xv,w2.y,acc[9]);
            acc[10]= fmaf(xv,w2.z,acc[10]); acc[11]= fmaf(xv,w2.w,acc[11]);
            acc[12]= fmaf(xv,w3.x,acc[12]); acc[13]= fmaf(xv,w3.y,acc[13]);
            acc[14]= fmaf(xv,w3.z,acc[14]); acc[15]= fmaf(xv,w3.w,acc[15]);
        }
    }
    #pragma unroll
    for (int j=0;j<16;++j) {
        int c = cg*16 + j;
        if (c < NOUT) {
            float v = acc[j];
            if (RELU) v = lrelu_f(v);
            Y[(row0+r)*ypitch + c] = v;
        }
    }
}

// ---------------- |s|^2 ----------------
__global__ void sq_kernel(const float* __restrict__ S, float* __restrict__ SQ)
{
    int i = blockIdx.x*blockDim.x + threadIdx.x;
    const float4* sp = reinterpret_cast<const float4*>(&S[(long)i*8]);
    float4 a = sp[0], b = sp[1];
    SQ[i] = a.x*a.x + a.y*a.y + a.z*a.z + a.w*a.w
          + b.x*b.x + b.y*b.y + b.z*b.z + b.w*b.w;
}

// ---------------- kNN: one query per wave, replace-max top-40 in registers ----------------
__device__ __forceinline__ float wave_max64(float x) {
    #pragma unroll
    for (int off = 32; off; off >>= 1) x = fmaxf(x, __shfl_xor(x, off));
    return x;   // all 64 lanes hold the wave max
}

#define KNN_WPB 8   // waves (=queries) per block

__global__ __launch_bounds__(64*KNN_WPB)
void knn_kernel(const float* __restrict__ S, const float* __restrict__ SQ,
                int* __restrict__ idx_out, float* __restrict__ w_out, int N)
{
    __shared__ __align__(16) float tile[9*256];   // [k][c] layout: 9KB
    const int tid  = threadIdx.x;
    const int lane = tid & 63;
    const int wv   = tid >> 6;
    const int q    = blockIdx.x*KNN_WPB + wv;

    // query coords (uniform per wave)
    const float4* qp = reinterpret_cast<const float4*>(&S[(long)q*8]);
    const float4 qa = qp[0], qb = qp[1];
    const float sqq = SQ[q];

    // top-40: one slot per lane on lanes 0..39
    float Rd = (lane < KNN) ? INFINITY : -INFINITY;
    int   Ri = 0;
    float tau = INFINITY;   // current worst-of-top40 (max over slots); wave-uniform
    int   vlane = 0;        // current victim (argmax) lane; wave-uniform

    for (int t0 = 0; t0 < N; t0 += 256) {
        __syncthreads();
        for (int i = tid; i < 9*256; i += 64*KNN_WPB) {
            int k = i >> 8, c = i & 255;
            tile[i] = (k < 8) ? S[(long)(t0 + c)*8 + k] : SQ[t0 + c];
        }
        __syncthreads();
        #pragma unroll
        for (int sub = 0; sub < 4; ++sub) {
            const int cb = sub*64 + lane;
            const float dot = qa.x*tile[0*256+cb] + qa.y*tile[1*256+cb]
                            + qa.z*tile[2*256+cb] + qa.w*tile[3*256+cb]
                            + qb.x*tile[4*256+cb] + qb.y*tile[5*256+cb]
                            + qb.z*tile[6*256+cb] + qb.w*tile[7*256+cb];
            float d2 = sqq + tile[8*256+cb] - 2.f*dot;
            const int c = t0 + sub*64 + lane;
            if (c == q) d2 = INFINITY;

            unsigned long long mask = __ballot(d2 < tau);
            while (mask) {
                const int l = __ffsll((long long)mask) - 1;
                mask &= mask - 1;
                const float bd = __int_as_float(__builtin_amdgcn_readlane(__float_as_int(d2), l));
                if (bd < tau) {
                    const int bc = t0 + sub*64 + l;
                    if (lane == vlane) { Rd = bd; Ri = bc; }
                    tau = wave_max64(Rd);
                    const unsigned long long vm = __ballot(Rd == tau);
                    vlane = __ffsll((long long)vm) - 1;
                }
            }
        }
    }
    if (lane < KNN) {
        idx_out[(long)q*KNN + lane] = Ri;
        w_out[(long)q*KNN + lane]   = expf(-10.f * Rd);
    }
}

// ---------------- GravNet aggregate: [mean(h*w), max(h*w), x12] -> 56 ----------------
__global__ void gravnet_agg(const float* __restrict__ H /*pitch 24*/,
                            const int* __restrict__ idx, const float* __restrict__ wgt,
                            const float* __restrict__ X12, float* __restrict__ OUT /*pitch 56*/)
{
    int n = blockIdx.x*blockDim.x + threadIdx.x;
    float sum[22], mx[22];
    #pragma unroll
    for (int f=0;f<22;++f){ sum[f]=0.f; mx[f]=-INFINITY; }
    #pragma unroll 1
    for (int k=0;k<KNN;++k) {
        int j = idx[(long)n*KNN+k];
        float wv = wgt[(long)n*KNN+k];
        const float4* hp = reinterpret_cast<const float4*>(&H[(long)j*24]);
        float4 h0=hp[0],h1=hp[1],h2=hp[2],h3=hp[3],h4=hp[4],h5=hp[5];
        float hv[24] = {h0.x,h0.y,h0.z,h0.w, h1.x,h1.y,h1.z,h1.w,
                        h2.x,h2.y,h2.z,h2.w, h3.x,h3.y,h3.z,h3.w,
                        h4.x,h4.y,h4.z,h4.w, h5.x,h5.y,h5.z,h5.w};
        #pragma unroll
        for (int f=0;f<22;++f){ float m = hv[f]*wv; sum[f]+=m; mx[f]=fmaxf(mx[f],m); }
    }
    float* o = &OUT[(long)n*56];
    #pragma unroll
    for (int f=0;f<22;++f){ o[f] = sum[f]*(1.f/40.f); o[22+f] = mx[f]; }
    const float* xp = &X12[(long)n*12];
    #pragma unroll
    for (int d=0;d<12;++d) o[44+d] = xp[d];
}

// ---------------- GraphConv neighbor sum ----------------
__global__ void graphconv_gather(const float* __restrict__ XG, const int* __restrict__ idx,
                                 const float* __restrict__ wgt, float* __restrict__ OUT)
{
    int n = blockIdx.x*blockDim.x + threadIdx.x;
    float acc[64];
    #pragma unroll
    for (int c=0;c<64;++c) acc[c]=0.f;
    #pragma unroll 1
    for (int k=0;k<KNN;++k) {
        int j = idx[(long)n*KNN+k];
        float wv = wgt[(long)n*KNN+k];
        const float4* xp = reinterpret_cast<const float4*>(&XG[(long)j*64]);
        #pragma unroll
        for (int c=0;c<16;++c) {
            float4 v = xp[c];
            acc[4*c+0] = fmaf(v.x,wv,acc[4*c+0]);
            acc[4*c+1] = fmaf(v.y,wv,acc[4*c+1]);
            acc[4*c+2] = fmaf(v.z,wv,acc[4*c+2]);
            acc[4*c+3] = fmaf(v.w,wv,acc[4*c+3]);
        }
    }
    float4* op = reinterpret_cast<float4*>(&OUT[(long)n*64]);
    #pragma unroll
    for (int c=0;c<16;++c) op[c] = make_float4(acc[4*c],acc[4*c+1],acc[4*c+2],acc[4*c+3]);
}

// ---------------- concat [xc(64), cand_ids(6), x0(12)] -> 82 ----------------
__global__ void cat82_kernel(const float* __restrict__ xc, const float* __restrict__ ids,
                             const float* __restrict__ x0, float* __restrict__ Z)
{
    int n = blockIdx.x*blockDim.x + threadIdx.x;
    float* z = &Z[(long)n*82];
    const float* a = &xc[(long)n*64];
    #pragma unroll 8
    for (int c=0;c<64;++c) z[c] = a[c];
    const float* b = &ids[(long)n*6];
    #pragma unroll
    for (int j=0;j<6;++j) z[64+j] = b[j];
    const float* d = &x0[(long)n*12];
    #pragma unroll
    for (int j=0;j<12;++j) z[70+j] = d[j];
}

// ---------------- passthrough outputs ----------------
__global__ void copyout_kernel(const int* __restrict__ gid, const float* __restrict__ gy,
                               const int* __restrict__ cid, const float* __restrict__ cy,
                               float* __restrict__ out, int N)
{
    long i = (long)blockIdx.x*blockDim.x + threadIdx.x;
    long n = N;
    if (i < n)            out[12*n + i]         = (float)gid[i];
    else if (i < 7*n)     out[13*n + (i - n)]   = gy[i - n];
    else if (i < 8*n)     out[19*n + (i - 7*n)] = (float)cid[i - 7*n];
    else if (i < 14*n)    out[20*n + (i - 8*n)] = cy[i - 8*n];
}

extern "C" void kernel_launch(void* const* d_in, const int* in_sizes, int n_in,
                              void* d_out, int out_size, void* d_ws, size_t ws_size,
                              hipStream_t stream)
{
    const float* x0     = (const float*)d_in[0];
    const float* ygen   = (const float*)d_in[1];
    const float* ycand  = (const float*)d_in[2];
    const int*   ygenid = (const int*)d_in[3];
    const int*   ycandid= (const int*)d_in[4];
    const float* n1W0=(const float*)d_in[5],  *n1b0=(const float*)d_in[6];
    const float* n1W1=(const float*)d_in[7],  *n1b1=(const float*)d_in[8];
    const float* n1W2=(const float*)d_in[9],  *n1b2=(const float*)d_in[10];
    const float* gWs =(const float*)d_in[11], *gbs =(const float*)d_in[12];
    const float* gWh =(const float*)d_in[13], *gbh =(const float*)d_in[14];
    const float* gWo =(const float*)d_in[15], *gbo =(const float*)d_in[16];
    const float* c2Wrel=(const float*)d_in[17], *c2brel=(const float*)d_in[18];
    const float* c2Wroot=(const float*)d_in[19];
    const float* n2W0=(const float*)d_in[20], *n2b0=(const float*)d_in[21];
    const float* n2W1=(const float*)d_in[22], *n2b1=(const float*)d_in[23];
    const float* n2W2=(const float*)d_in[24], *n2b2=(const float*)d_in[25];
    const float* n2W3=(const float*)d_in[26], *n2b3=(const float*)d_in[27];
    const float* n3W0=(const float*)d_in[28], *n3b0=(const float*)d_in[29];
    const float* n3W1=(const float*)d_in[30], *n3b1=(const float*)d_in[31];
    const float* n3W2=(const float*)d_in[32], *n3b2=(const float*)d_in[33];
    const float* n3W3=(const float*)d_in[34], *n3b3=(const float*)d_in[35];

    const int N = in_sizes[0] / 12;      // 16384
    float* ws = (float*)d_ws;
    size_t off = 0;
    auto alloc = [&](size_t cnt){ float* p = ws + off; off += cnt; return p; };
    float* A    = alloc((size_t)N*128);
    float* Bb   = alloc((size_t)N*128);
    float* x12  = alloc((size_t)N*12);
    float* s    = alloc((size_t)N*8);
    float* sq   = alloc((size_t)N);
    float* h    = alloc((size_t)N*24);
    int*   idxb = (int*)alloc((size_t)N*KNN);
    float* wb   = alloc((size_t)N*KNN);
    float* xg   = alloc((size_t)N*64);
    float* xc   = alloc((size_t)N*64);
    (void)ws_size; (void)n_in; (void)out_size;

    float* outF = (float*)d_out;
    const int GB = N / 64;               // 256 blocks

    // nn1 encoder
    lin_kernel<12,64,true,false><<<GB,256,0,stream>>>(x0,  n1W0, n1b0, nullptr, nullptr, A,   64);
    lin_kernel<64,64,true,false><<<GB,256,0,stream>>>(A,   n1W1, n1b1, nullptr, nullptr, Bb,  64);
    lin_kernel<64,12,true,false><<<GB, 64,0,stream>>>(Bb,  n1W2, n1b2, nullptr, nullptr, x12, 12);
    // GravNet space/feature projections
    lin_kernel<12, 8,false,false><<<GB, 64,0,stream>>>(x12, gWs, gbs, nullptr, nullptr, s, 8);
    lin_kernel<12,22,false,false><<<GB,128,0,stream>>>(x12, gWh, gbh, nullptr, nullptr, h, 24);
    sq_kernel<<<N/256,256,0,stream>>>(s, sq);
    knn_kernel<<<N/KNN_WPB, 64*KNN_WPB, 0, stream>>>(s, sq, idxb, wb, N);
    gravnet_agg<<<GB,64,0,stream>>>(h, idxb, wb, x12, A);
    lin_kernel<56,64,false,false><<<GB,256,0,stream>>>(A, gWo, gbo, nullptr, nullptr, xg, 64);
    // GraphConv
    graphconv_gather<<<GB,64,0,stream>>>(xg, idxb, wb, Bb);
    lin_kernel<64,64,false,true><<<GB,256,0,stream>>>(Bb, c2Wrel, c2brel, xg, c2Wroot, xc, 64);
    // nn2 head -> cand_ids at d_out[0:6N]
    lin_kernel<64,126,true,false><<<GB,512,0,stream>>>(xc, n2W0, n2b0, nullptr, nullptr, A, 126);
    lin_kernel<126,126,true,false><<<GB,512,0,stream>>>(A,  n2W1, n2b1, nullptr, nullptr, Bb,126);
    lin_kernel<126,126,true,false><<<GB,512,0,stream>>>(Bb, n2W2, n2b2, nullptr, nullptr, A, 126);
    lin_kernel<126,6,true,false><<<GB, 64,0,stream>>>(A,  n2W3, n2b3, nullptr, nullptr, outF, 6);
    // nn3 head -> cand_p4 at d_out[6N:12N]
    cat82_kernel<<<N/256,256,0,stream>>>(xc, outF, x0, Bb);
    lin_kernel<82,126,true,false><<<GB,512,0,stream>>>(Bb, n3W0, n3b0, nullptr, nullptr, A, 126);
    lin_kernel<126,126,true,false><<<GB,512,0,stream>>>(A,  n3W1, n3b1, nullptr, nullptr, Bb,126);
    lin_kernel<126,126,true,false><<<GB,512,0,stream>>>(Bb, n3W2, n3b2, nullptr, nullptr, A, 126);
    lin_kernel<126,6,true,false><<<GB, 64,0,stream>>>(A,  n3W3, n3b3, nullptr, nullptr, outF + (size_t)N*6, 6);
    // passthrough outputs
    copyout_kernel<<<(14*N+255)/256,256,0,stream>>>(ygenid, ygen, ycandid, ycand, outF, N);
}

// Round 4
// 729.800 us; speedup vs baseline: 4.6482x; 1.5685x over previous
//
#include <hip/hip_runtime.h>
#include <math.h>

static constexpr int KNN = 40;

__device__ __forceinline__ float lrelu_f(float v){ return v >= 0.f ? v : 0.5f*v; }

// ---------------- generic fused linear: Y = act(X@W + b [+ X2@W2]) ----------------
template<int K, int NOUT, bool RELU, bool DUAL>
__global__ __launch_bounds__(64*((NOUT+15)/16))
void lin_kernel(const float* __restrict__ X, const float* __restrict__ W,
                const float* __restrict__ Bv,
                const float* __restrict__ X2, const float* __restrict__ W2,
                float* __restrict__ Y, int ypitch)
{
    constexpr int NP = ((NOUT+15)/16)*16;
    constexpr int CG = NP/16;
    constexpr int NTH = 64*CG;
    constexpr int KP = (K % 2 == 0) ? (K+1) : K;
    __shared__ __align__(16) float Xs[64*KP];
    __shared__ __align__(16) float Ws[K*NP];
    __shared__ __align__(16) float X2s[DUAL ? 64*KP : 4];
    __shared__ __align__(16) float W2s[DUAL ? K*NP : 4];
    __shared__ float Bs[NP];
    const int t  = threadIdx.x;
    const int r  = t & 63;
    const int cg = t >> 6;
    const long row0 = (long)blockIdx.x * 64;

    for (int i = t; i < K*NP; i += NTH) {
        int k = i / NP, c = i - k*NP;
        Ws[i] = (c < NOUT) ? W[k*NOUT + c] : 0.f;
        if (DUAL) W2s[i] = (c < NOUT) ? W2[k*NOUT + c] : 0.f;
    }
    for (int i = t; i < NP; i += NTH) Bs[i] = (i < NOUT) ? Bv[i] : 0.f;
    for (int i = t; i < 64*K; i += NTH) {
        int rr = i / K, cc = i - rr*K;
        Xs[rr*KP + cc] = X[(row0+rr)*K + cc];
        if (DUAL) X2s[rr*KP + cc] = X2[(row0+rr)*K + cc];
    }
    __syncthreads();

    float acc[16];
    #pragma unroll
    for (int j=0;j<16;++j) acc[j] = Bs[cg*16+j];

    {
        const float* xrow = &Xs[r*KP];
        #pragma unroll 4
        for (int k=0;k<K;++k) {
            float xv = xrow[k];
            const float4* wp = reinterpret_cast<const float4*>(&Ws[k*NP + cg*16]);
            float4 w0 = wp[0], w1 = wp[1], w2 = wp[2], w3 = wp[3];
            acc[0] = fmaf(xv,w0.x,acc[0]);  acc[1] = fmaf(xv,w0.y,acc[1]);
            acc[2] = fmaf(xv,w0.z,acc[2]);  acc[3] = fmaf(xv,w0.w,acc[3]);
            acc[4] = fmaf(xv,w1.x,acc[4]);  acc[5] = fmaf(xv,w1.y,acc[5]);
            acc[6] = fmaf(xv,w1.z,acc[6]);  acc[7] = fmaf(xv,w1.w,acc[7]);
            acc[8] = fmaf(xv,w2.x,acc[8]);  acc[9] = fmaf(xv,w2.y,acc[9]);
            acc[10]= fmaf(xv,w2.z,acc[10]); acc[11]= fmaf(xv,w2.w,acc[11]);
            acc[12]= fmaf(xv,w3.x,acc[12]); acc[13]= fmaf(xv,w3.y,acc[13]);
            acc[14]= fmaf(xv,w3.z,acc[14]); acc[15]= fmaf(xv,w3.w,acc[15]);
        }
    }
    if (DUAL) {
        const float* xrow = &X2s[r*KP];
        #pragma unroll 4
        for (int k=0;k<K;++k) {
            float xv = xrow[k];
            const float4* wp = reinterpret_cast<const float4*>(&W2s[k*NP + cg*16]);
            float4 w0 = wp[0], w1 = wp[1], w2 = wp[2], w3 = wp[3];
            acc[0] = fmaf(xv,w0.x,acc[0]);  acc[1] = fmaf(xv,w0.y,acc[1]);
            acc[2] = fmaf(xv,w0.z,acc[2]);  acc[3] = fmaf(xv,w0.w,acc[3]);
            acc[4] = fmaf(xv,w1.x,acc[4]);  acc[5] = fmaf(xv,w1.y,acc[5]);
            acc[6] = fmaf(xv,w1.z,acc[6]);  acc[7] = fmaf(xv,w1.w,acc[7]);
            acc[8] = fmaf(xv,w2.x,acc[8]);  acc[9] = fmaf(xv,w2.y,acc[9]);
            acc[10]= fmaf(xv,w2.z,acc[10]); acc[11]= fmaf(xv,w2.w,acc[11]);
            acc[12]= fmaf(xv,w3.x,acc[12]); acc[13]= fmaf(xv,w3.y,acc[13]);
            acc[14]= fmaf(xv,w3.z,acc[14]); acc[15]= fmaf(xv,w3.w,acc[15]);
        }
    }
    #pragma unroll
    for (int j=0;j<16;++j) {
        int c = cg*16 + j;
        if (c < NOUT) {
            float v = acc[j];
            if (RELU) v = lrelu_f(v);
            Y[(row0+r)*ypitch + c] = v;
        }
    }
}

// ---------------- |s|^2 ----------------
__global__ void sq_kernel(const float* __restrict__ S, float* __restrict__ SQ)
{
    int i = blockIdx.x*blockDim.x + threadIdx.x;
    const float4* sp = reinterpret_cast<const float4*>(&S[(long)i*8]);
    float4 a = sp[0], b = sp[1];
    SQ[i] = a.x*a.x + a.y*a.y + a.z*a.z + a.w*a.w
          + b.x*b.x + b.y*b.y + b.z*b.z + b.w*b.w;
}

// ---------------- kNN round 4 ----------------
// 4 queries per wave, 4 candidates per lane, per-lane top-8 packed keys,
// DPP extract-min merge. Key = (d2_bits & ~0xFF) | (tile<<2 | i).
template<int C>
__device__ __forceinline__ unsigned dpp_umin(unsigned x){
    unsigned y = (unsigned)__builtin_amdgcn_update_dpp((int)x, (int)x, C, 0xf, 0xf, false);
    return x < y ? x : y;
}
__device__ __forceinline__ unsigned wave_umin64(unsigned x){
    x = dpp_umin<0x111>(x);   // row_shr:1
    x = dpp_umin<0x112>(x);   // row_shr:2
    x = dpp_umin<0x114>(x);   // row_shr:4
    x = dpp_umin<0x118>(x);   // row_shr:8
    x = dpp_umin<0x142>(x);   // row_bcast:15
    x = dpp_umin<0x143>(x);   // row_bcast:31
    return x;                 // lane 63 holds min over all 64 lanes
}

#define KNN_WPB 4   // waves per block
#define QPW 4       // queries per wave
#define LTOP 8      // per-lane local top-8

__global__ __launch_bounds__(64*KNN_WPB)
void knn_kernel(const float* __restrict__ S, const float* __restrict__ SQ,
                int* __restrict__ idx_out, float* __restrict__ w_out, int N)
{
    __shared__ __align__(16) float tile[9*256];   // [k][c], 9 KB
    const int tid  = threadIdx.x;
    const int lane = tid & 63;
    const int wv   = tid >> 6;
    const int q0   = (blockIdx.x*KNN_WPB + wv)*QPW;

    // query coords: qa[qq][k], |s_q|^2
    float qa[QPW][8]; float sqq[QPW];
    #pragma unroll
    for (int qq=0; qq<QPW; ++qq) {
        const float4* qp = reinterpret_cast<const float4*>(&S[(long)(q0+qq)*8]);
        float4 a = qp[0], b = qp[1];
        qa[qq][0]=a.x; qa[qq][1]=a.y; qa[qq][2]=a.z; qa[qq][3]=a.w;
        qa[qq][4]=b.x; qa[qq][5]=b.y; qa[qq][6]=b.z; qa[qq][7]=b.w;
        sqq[qq] = SQ[q0+qq];
    }

    unsigned slot[QPW][LTOP];
    unsigned lmax[QPW];
    #pragma unroll
    for (int qq=0; qq<QPW; ++qq) {
        lmax[qq] = 0xFFFFFFFFu;
        #pragma unroll
        for (int s2=0; s2<LTOP; ++s2) slot[qq][s2] = 0xFFFFFFFFu;
    }

    const int NT = N >> 8;   // 64 tiles of 256 candidates
    #pragma unroll 1
    for (int t = 0; t < NT; ++t) {
        __syncthreads();
        {   // stage tile: 256 threads, candidate c = tid
            const float4* cp = reinterpret_cast<const float4*>(&S[(long)(t*256 + tid)*8]);
            float4 a = cp[0], b = cp[1];
            tile[0*256+tid]=a.x; tile[1*256+tid]=a.y; tile[2*256+tid]=a.z; tile[3*256+tid]=a.w;
            tile[4*256+tid]=b.x; tile[5*256+tid]=b.y; tile[6*256+tid]=b.z; tile[7*256+tid]=b.w;
            tile[8*256+tid]=SQ[t*256 + tid];
        }
        __syncthreads();

        float dot[QPW][4];
        #pragma unroll
        for (int qq=0;qq<QPW;++qq){ dot[qq][0]=0.f; dot[qq][1]=0.f; dot[qq][2]=0.f; dot[qq][3]=0.f; }
        #pragma unroll
        for (int k=0;k<8;++k){
            float4 v = *reinterpret_cast<const float4*>(&tile[k*256 + lane*4]);
            #pragma unroll
            for (int qq=0;qq<QPW;++qq){
                dot[qq][0] = fmaf(qa[qq][k], v.x, dot[qq][0]);
                dot[qq][1] = fmaf(qa[qq][k], v.y, dot[qq][1]);
                dot[qq][2] = fmaf(qa[qq][k], v.z, dot[qq][2]);
                dot[qq][3] = fmaf(qa[qq][k], v.w, dot[qq][3]);
            }
        }
        float4 sc = *reinterpret_cast<const float4*>(&tile[8*256 + lane*4]);
        const float scv[4] = {sc.x, sc.y, sc.z, sc.w};

        #pragma unroll
        for (int qq=0;qq<QPW;++qq){
            const int off = (q0+qq) - t*256;   // self index within tile (uniform)
            #pragma unroll
            for (int i=0;i<4;++i){
                float d2 = fmaf(-2.f, dot[qq][i], sqq[qq] + scv[i]);
                d2 = fmaxf(d2, 0.f);
                unsigned key = (__float_as_uint(d2) & 0xFFFFFF00u) | (unsigned)((t<<2)|i);
                if (off == lane*4 + i) key = 0xFFFFFFFFu;   // exclude self
                unsigned mx = lmax[qq];
                if (key < mx) {
                    bool done = false;
                    #pragma unroll
                    for (int s2=0; s2<LTOP; ++s2) {
                        if (!done && slot[qq][s2]==mx){ slot[qq][s2]=key; done=true; }
                    }
                    unsigned m2 = slot[qq][0];
                    #pragma unroll
                    for (int s2=1; s2<LTOP; ++s2) m2 = m2 > slot[qq][s2] ? m2 : slot[qq][s2];
                    lmax[qq] = m2;
                }
            }
        }
    }

    // ---- merge: per query, 40 extract-mins over 64 lanes x 8 slots ----
    #pragma unroll
    for (int qq=0; qq<QPW; ++qq) {
        const int q = q0 + qq;
        unsigned lmin = slot[qq][0];
        #pragma unroll
        for (int s2=1; s2<LTOP; ++s2) lmin = lmin < slot[qq][s2] ? lmin : slot[qq][s2];

        unsigned savedK = 0; int savedC = 0;
        #pragma unroll 1
        for (int p=0; p<KNN; ++p) {
            unsigned red = wave_umin64(lmin);
            unsigned gm = (unsigned)__builtin_amdgcn_readlane((int)red, 63);
            unsigned long long bal = __ballot(lmin == gm);
            int owner = __ffsll((long long)bal) - 1;
            if (lane == owner) {
                bool done = false;
                #pragma unroll
                for (int s2=0; s2<LTOP; ++s2) {
                    if (!done && slot[qq][s2]==gm){ slot[qq][s2]=0xFFFFFFFFu; done=true; }
                }
                unsigned m2 = slot[qq][0];
                #pragma unroll
                for (int s2=1; s2<LTOP; ++s2) m2 = m2 < slot[qq][s2] ? m2 : slot[qq][s2];
                lmin = m2;
            }
            if (lane == p) { savedK = gm; savedC = owner; }
        }
        if (lane < KNN) {
            const int tl = (int)((savedK >> 2) & 0x3Fu);
            const int ii = (int)(savedK & 3u);
            const int c  = tl*256 + savedC*4 + ii;
            const float d2 = __uint_as_float(savedK & 0xFFFFFF00u);
            idx_out[(long)q*KNN + lane] = c;
            w_out[(long)q*KNN + lane]   = expf(-10.f * d2);
        }
    }
}

// ---------------- GravNet aggregate: [mean(h*w), max(h*w), x12] -> 56 ----------------
__global__ void gravnet_agg(const float* __restrict__ H /*pitch 24*/,
                            const int* __restrict__ idx, const float* __restrict__ wgt,
                            const float* __restrict__ X12, float* __restrict__ OUT /*pitch 56*/)
{
    int n = blockIdx.x*blockDim.x + threadIdx.x;
    float sum[22], mx[22];
    #pragma unroll
    for (int f=0;f<22;++f){ sum[f]=0.f; mx[f]=-INFINITY; }
    #pragma unroll 1
    for (int k=0;k<KNN;++k) {
        int j = idx[(long)n*KNN+k];
        float wv = wgt[(long)n*KNN+k];
        const float4* hp = reinterpret_cast<const float4*>(&H[(long)j*24]);
        float4 h0=hp[0],h1=hp[1],h2=hp[2],h3=hp[3],h4=hp[4],h5=hp[5];
        float hv[24] = {h0.x,h0.y,h0.z,h0.w, h1.x,h1.y,h1.z,h1.w,
                        h2.x,h2.y,h2.z,h2.w, h3.x,h3.y,h3.z,h3.w,
                        h4.x,h4.y,h4.z,h4.w, h5.x,h5.y,h5.z,h5.w};
        #pragma unroll
        for (int f=0;f<22;++f){ float m = hv[f]*wv; sum[f]+=m; mx[f]=fmaxf(mx[f],m); }
    }
    float* o = &OUT[(long)n*56];
    #pragma unroll
    for (int f=0;f<22;++f){ o[f] = sum[f]*(1.f/40.f); o[22+f] = mx[f]; }
    const float* xp = &X12[(long)n*12];
    #pragma unroll
    for (int d=0;d<12;++d) o[44+d] = xp[d];
}

// ---------------- GraphConv neighbor sum ----------------
__global__ void graphconv_gather(const float* __restrict__ XG, const int* __restrict__ idx,
                                 const float* __restrict__ wgt, float* __restrict__ OUT)
{
    int n = blockIdx.x*blockDim.x + threadIdx.x;
    float acc[64];
    #pragma unroll
    for (int c=0;c<64;++c) acc[c]=0.f;
    #pragma unroll 1
    for (int k=0;k<KNN;++k) {
        int j = idx[(long)n*KNN+k];
        float wv = wgt[(long)n*KNN+k];
        const float4* xp = reinterpret_cast<const float4*>(&XG[(long)j*64]);
        #pragma unroll
        for (int c=0;c<16;++c) {
            float4 v = xp[c];
            acc[4*c+0] = fmaf(v.x,wv,acc[4*c+0]);
            acc[4*c+1] = fmaf(v.y,wv,acc[4*c+1]);
            acc[4*c+2] = fmaf(v.z,wv,acc[4*c+2]);
            acc[4*c+3] = fmaf(v.w,wv,acc[4*c+3]);
        }
    }
    float4* op = reinterpret_cast<float4*>(&OUT[(long)n*64]);
    #pragma unroll
    for (int c=0;c<16;++c) op[c] = make_float4(acc[4*c],acc[4*c+1],acc[4*c+2],acc[4*c+3]);
}

// ---------------- concat [xc(64), cand_ids(6), x0(12)] -> 82 ----------------
__global__ void cat82_kernel(const float* __restrict__ xc, const float* __restrict__ ids,
                             const float* __restrict__ x0, float* __restrict__ Z)
{
    int n = blockIdx.x*blockDim.x + threadIdx.x;
    float* z = &Z[(long)n*82];
    const float* a = &xc[(long)n*64];
    #pragma unroll 8
    for (int c=0;c<64;++c) z[c] = a[c];
    const float* b = &ids[(long)n*6];
    #pragma unroll
    for (int j=0;j<6;++j) z[64+j] = b[j];
    const float* d = &x0[(long)n*12];
    #pragma unroll
    for (int j=0;j<12;++j) z[70+j] = d[j];
}

// ---------------- passthrough outputs ----------------
__global__ void copyout_kernel(const int* __restrict__ gid, const float* __restrict__ gy,
                               const int* __restrict__ cid, const float* __restrict__ cy,
                               float* __restrict__ out, int N)
{
    long i = (long)blockIdx.x*blockDim.x + threadIdx.x;
    long n = N;
    if (i < n)            out[12*n + i]         = (float)gid[i];
    else if (i < 7*n)     out[13*n + (i - n)]   = gy[i - n];
    else if (i < 8*n)     out[19*n + (i - 7*n)] = (float)cid[i - 7*n];
    else if (i < 14*n)    out[20*n + (i - 8*n)] = cy[i - 8*n];
}

extern "C" void kernel_launch(void* const* d_in, const int* in_sizes, int n_in,
                              void* d_out, int out_size, void* d_ws, size_t ws_size,
                              hipStream_t stream)
{
    const float* x0     = (const float*)d_in[0];
    const float* ygen   = (const float*)d_in[1];
    const float* ycand  = (const float*)d_in[2];
    const int*   ygenid = (const int*)d_in[3];
    const int*   ycandid= (const int*)d_in[4];
    const float* n1W0=(const float*)d_in[5],  *n1b0=(const float*)d_in[6];
    const float* n1W1=(const float*)d_in[7],  *n1b1=(const float*)d_in[8];
    const float* n1W2=(const float*)d_in[9],  *n1b2=(const float*)d_in[10];
    const float* gWs =(const float*)d_in[11], *gbs =(const float*)d_in[12];
    const float* gWh =(const float*)d_in[13], *gbh =(const float*)d_in[14];
    const float* gWo =(const float*)d_in[15], *gbo =(const float*)d_in[16];
    const float* c2Wrel=(const float*)d_in[17], *c2brel=(const float*)d_in[18];
    const float* c2Wroot=(const float*)d_in[19];
    const float* n2W0=(const float*)d_in[20], *n2b0=(const float*)d_in[21];
    const float* n2W1=(const float*)d_in[22], *n2b1=(const float*)d_in[23];
    const float* n2W2=(const float*)d_in[24], *n2b2=(const float*)d_in[25];
    const float* n2W3=(const float*)d_in[26], *n2b3=(const float*)d_in[27];
    const float* n3W0=(const float*)d_in[28], *n3b0=(const float*)d_in[29];
    const float* n3W1=(const float*)d_in[30], *n3b1=(const float*)d_in[31];
    const float* n3W2=(const float*)d_in[32], *n3b2=(const float*)d_in[33];
    const float* n3W3=(const float*)d_in[34], *n3b3=(const float*)d_in[35];

    const int N = in_sizes[0] / 12;      // 16384
    float* ws = (float*)d_ws;
    size_t off = 0;
    auto alloc = [&](size_t cnt){ float* p = ws + off; off += cnt; return p; };
    float* A    = alloc((size_t)N*128);
    float* Bb   = alloc((size_t)N*128);
    float* x12  = alloc((size_t)N*12);
    float* s    = alloc((size_t)N*8);
    float* sq   = alloc((size_t)N);
    float* h    = alloc((size_t)N*24);
    int*   idxb = (int*)alloc((size_t)N*KNN);
    float* wb   = alloc((size_t)N*KNN);
    float* xg   = alloc((size_t)N*64);
    float* xc   = alloc((size_t)N*64);
    (void)ws_size; (void)n_in; (void)out_size;

    float* outF = (float*)d_out;
    const int GB = N / 64;               // 256 blocks

    // nn1 encoder
    lin_kernel<12,64,true,false><<<GB,256,0,stream>>>(x0,  n1W0, n1b0, nullptr, nullptr, A,   64);
    lin_kernel<64,64,true,false><<<GB,256,0,stream>>>(A,   n1W1, n1b1, nullptr, nullptr, Bb,  64);
    lin_kernel<64,12,true,false><<<GB, 64,0,stream>>>(Bb,  n1W2, n1b2, nullptr, nullptr, x12, 12);
    // GravNet space/feature projections
    lin_kernel<12, 8,false,false><<<GB, 64,0,stream>>>(x12, gWs, gbs, nullptr, nullptr, s, 8);
    lin_kernel<12,22,false,false><<<GB,128,0,stream>>>(x12, gWh, gbh, nullptr, nullptr, h, 24);
    sq_kernel<<<N/256,256,0,stream>>>(s, sq);
    knn_kernel<<<N/(KNN_WPB*QPW), 64*KNN_WPB, 0, stream>>>(s, sq, idxb, wb, N);
    gravnet_agg<<<GB,64,0,stream>>>(h, idxb, wb, x12, A);
    lin_kernel<56,64,false,false><<<GB,256,0,stream>>>(A, gWo, gbo, nullptr, nullptr, xg, 64);
    // GraphConv
    graphconv_gather<<<GB,64,0,stream>>>(xg, idxb, wb, Bb);
    lin_kernel<64,64,false,true><<<GB,256,0,stream>>>(Bb, c2Wrel, c2brel, xg, c2Wroot, xc, 64);
    // nn2 head -> cand_ids at d_out[0:6N]
    lin_kernel<64,126,true,false><<<GB,512,0,stream>>>(xc, n2W0, n2b0, nullptr, nullptr, A, 126);
    lin_kernel<126,126,true,false><<<GB,512,0,stream>>>(A,  n2W1, n2b1, nullptr, nullptr, Bb,126);
    lin_kernel<126,126,true,false><<<GB,512,0,stream>>>(Bb, n2W2, n2b2, nullptr, nullptr, A, 126);
    lin_kernel<126,6,true,false><<<GB, 64,0,stream>>>(A,  n2W3, n2b3, nullptr, nullptr, outF, 6);
    // nn3 head -> cand_p4 at d_out[6N:12N]
    cat82_kernel<<<N/256,256,0,stream>>>(xc, outF, x0, Bb);
    lin_kernel<82,126,true,false><<<GB,512,0,stream>>>(Bb, n3W0, n3b0, nullptr, nullptr, A, 126);
    lin_kernel<126,126,true,false><<<GB,512,0,stream>>>(A,  n3W1, n3b1, nullptr, nullptr, Bb,126);
    lin_kernel<126,126,true,false><<<GB,512,0,stream>>>(Bb, n3W2, n3b2, nullptr, nullptr, A, 126);
    lin_kernel<126,6,true,false><<<GB, 64,0,stream>>>(A,  n3W3, n3b3, nullptr, nullptr, outF + (size_t)N*6, 6);
    // passthrough outputs
    copyout_kernel<<<(14*N+255)/256,256,0,stream>>>(ygenid, ygen, ycandid, ycand, outF, N);
}

// Round 5
// 359.515 us; speedup vs baseline: 9.4357x; 2.0300x over previous
//
#include <hip/hip_runtime.h>
#include <math.h>

static constexpr int KNN = 40;

__device__ __forceinline__ float lrelu_f(float v){ return v >= 0.f ? v : 0.5f*v; }

#define FMA16(xv, wbase) do{ const float4* wp_ = reinterpret_cast<const float4*>(wbase); \
  float4 w0_=wp_[0],w1_=wp_[1],w2_=wp_[2],w3_=wp_[3]; \
  acc[0]=fmaf(xv,w0_.x,acc[0]); acc[1]=fmaf(xv,w0_.y,acc[1]); acc[2]=fmaf(xv,w0_.z,acc[2]); acc[3]=fmaf(xv,w0_.w,acc[3]); \
  acc[4]=fmaf(xv,w1_.x,acc[4]); acc[5]=fmaf(xv,w1_.y,acc[5]); acc[6]=fmaf(xv,w1_.z,acc[6]); acc[7]=fmaf(xv,w1_.w,acc[7]); \
  acc[8]=fmaf(xv,w2_.x,acc[8]); acc[9]=fmaf(xv,w2_.y,acc[9]); acc[10]=fmaf(xv,w2_.z,acc[10]); acc[11]=fmaf(xv,w2_.w,acc[11]); \
  acc[12]=fmaf(xv,w3_.x,acc[12]); acc[13]=fmaf(xv,w3_.y,acc[13]); acc[14]=fmaf(xv,w3_.z,acc[14]); acc[15]=fmaf(xv,w3_.w,acc[15]); }while(0)

// ---- in-block linear stage: Y(r,c) = act( Xs(r,:) @ W + b ), 64 rows per block ----
// Xs may be LDS or global (points at block's row 0). Ws/Bs are LDS scratch.
template<int K, int NOUT, bool RELU, int NTH>
__device__ __forceinline__
void lin_lds(const float* __restrict__ Xs, int xpitch,
             const float* __restrict__ W, const float* __restrict__ Bv,
             float* __restrict__ Ws, float* __restrict__ Bs,
             float* __restrict__ Y, int ypitch, int tid)
{
    constexpr int NP  = ((NOUT+15)/16)*16;
    constexpr int CGS = NP/16;
    for (int i = tid; i < K*NP; i += NTH) {
        int k = i / NP, c = i - k*NP;
        Ws[i] = (c < NOUT) ? W[k*NOUT + c] : 0.f;
    }
    for (int i = tid; i < NP; i += NTH) Bs[i] = (i < NOUT) ? Bv[i] : 0.f;
    __syncthreads();
    const int r = tid & 63;
    for (int cg = tid >> 6; cg < CGS; cg += (NTH >> 6)) {
        float acc[16];
        #pragma unroll
        for (int j=0;j<16;++j) acc[j] = Bs[cg*16+j];
        const float* xrow = &Xs[(long)r*xpitch];
        #pragma unroll 4
        for (int k=0;k<K;++k) { const float xv = xrow[k]; FMA16(xv, &Ws[k*NP + cg*16]); }
        #pragma unroll
        for (int j=0;j<16;++j) {
            int c = cg*16 + j;
            if (c < NOUT) { float v = acc[j]; if (RELU) v = lrelu_f(v); Y[(long)r*ypitch + c] = v; }
        }
    }
    __syncthreads();
}

// dual: Y = Xs@W + b + X2s@W2 (no activation)
template<int K, int NOUT, int NTH>
__device__ __forceinline__
void lin_lds_dual(const float* __restrict__ Xs, int xp, const float* __restrict__ X2s, int xp2,
                  const float* __restrict__ W, const float* __restrict__ Bv, const float* __restrict__ W2,
                  float* __restrict__ Ws, float* __restrict__ Ws2, float* __restrict__ Bs,
                  float* __restrict__ Y, int ypitch, int tid)
{
    constexpr int NP  = ((NOUT+15)/16)*16;
    constexpr int CGS = NP/16;
    for (int i = tid; i < K*NP; i += NTH) {
        int k = i / NP, c = i - k*NP;
        Ws[i]  = (c < NOUT) ? W[k*NOUT + c]  : 0.f;
        Ws2[i] = (c < NOUT) ? W2[k*NOUT + c] : 0.f;
    }
    for (int i = tid; i < NP; i += NTH) Bs[i] = (i < NOUT) ? Bv[i] : 0.f;
    __syncthreads();
    const int r = tid & 63;
    for (int cg = tid >> 6; cg < CGS; cg += (NTH >> 6)) {
        float acc[16];
        #pragma unroll
        for (int j=0;j<16;++j) acc[j] = Bs[cg*16+j];
        {
            const float* xrow = &Xs[(long)r*xp];
            #pragma unroll 4
            for (int k=0;k<K;++k) { const float xv = xrow[k]; FMA16(xv, &Ws[k*NP + cg*16]); }
        }
        {
            const float* xrow = &X2s[(long)r*xp2];
            #pragma unroll 4
            for (int k=0;k<K;++k) { const float xv = xrow[k]; FMA16(xv, &Ws2[k*NP + cg*16]); }
        }
        #pragma unroll
        for (int j=0;j<16;++j) {
            int c = cg*16 + j;
            if (c < NOUT) Y[(long)r*ypitch + c] = acc[j];
        }
    }
    __syncthreads();
}

// ---------------- F1: nn1 encoder + gWs + gWh + |s|^2 ----------------
__global__ __launch_bounds__(256)
void f1_encoder(const float* __restrict__ x0,
                const float* n1W0,const float* n1b0,const float* n1W1,const float* n1b1,
                const float* n1W2,const float* n1b2,
                const float* gWs,const float* gbs,const float* gWh,const float* gbh,
                float* __restrict__ x12g, float* __restrict__ sg,
                float* __restrict__ sqg, float* __restrict__ hg)
{
    __shared__ float A1[64*65], A2[64*65], Ss[64*9];
    __shared__ float Ws[64*128], Bs[128];
    const int tid = threadIdx.x;
    const long row0 = (long)blockIdx.x*64;
    lin_lds<12,64,true,256>(x0+row0*12,12, n1W0,n1b0, Ws,Bs, A1,65, tid);
    lin_lds<64,64,true,256>(A1,65, n1W1,n1b1, Ws,Bs, A2,65, tid);
    lin_lds<64,12,true,256>(A2,65, n1W2,n1b2, Ws,Bs, A1,13, tid);
    for (int i=tid;i<64*12;i+=256){ int r=i/12,c=i-r*12; x12g[(row0+r)*12+c]=A1[r*13+c]; }
    lin_lds<12,8,false,256>(A1,13, gWs,gbs, Ws,Bs, Ss,9, tid);
    lin_lds<12,22,false,256>(A1,13, gWh,gbh, Ws,Bs, hg+row0*24,24, tid);
    if (tid < 64) {
        float acc = 0.f;
        #pragma unroll
        for (int k=0;k<8;++k){ float v=Ss[tid*9+k]; sg[(row0+tid)*8+k]=v; acc=fmaf(v,v,acc); }
        sqg[row0+tid] = acc;
    }
}

// ---------------- kNN: 4 q/wave, 4 cand/lane, per-lane top-2, DPP merge ----------------
template<int C>
__device__ __forceinline__ unsigned dpp_umin(unsigned x){
    unsigned y = (unsigned)__builtin_amdgcn_update_dpp((int)x, (int)x, C, 0xf, 0xf, false);
    return x < y ? x : y;
}
__device__ __forceinline__ unsigned wave_umin64(unsigned x){
    x = dpp_umin<0x111>(x);
    x = dpp_umin<0x112>(x);
    x = dpp_umin<0x114>(x);
    x = dpp_umin<0x118>(x);
    x = dpp_umin<0x142>(x);
    x = dpp_umin<0x143>(x);
    return x;   // lane 63 holds the wave min
}

#define KNN_WPB 4
#define QPW 4

__global__ __launch_bounds__(256)
void knn_kernel(const float* __restrict__ S, const float* __restrict__ SQ,
                int* __restrict__ idx_out, float* __restrict__ w_out, int N)
{
    __shared__ __align__(16) float tile[9*256];
    const int tid  = threadIdx.x;
    const int lane = tid & 63;
    const int wv   = tid >> 6;
    const int q0   = (blockIdx.x*KNN_WPB + wv)*QPW;

    float qa[QPW][8]; float sqq[QPW];
    #pragma unroll
    for (int qq=0; qq<QPW; ++qq) {
        const float4* qp = reinterpret_cast<const float4*>(&S[(long)(q0+qq)*8]);
        float4 a = qp[0], b = qp[1];
        qa[qq][0]=a.x; qa[qq][1]=a.y; qa[qq][2]=a.z; qa[qq][3]=a.w;
        qa[qq][4]=b.x; qa[qq][5]=b.y; qa[qq][6]=b.z; qa[qq][7]=b.w;
        sqq[qq] = SQ[q0+qq];
    }

    unsigned s0[QPW], s1[QPW], lmax[QPW];
    #pragma unroll
    for (int qq=0; qq<QPW; ++qq){ s0[qq]=0xFFFFFFFFu; s1[qq]=0xFFFFFFFFu; lmax[qq]=0xFFFFFFFFu; }

    const int NT = N >> 8;
    #pragma unroll 1
    for (int t = 0; t < NT; ++t) {
        __syncthreads();
        {
            const float4* cp = reinterpret_cast<const float4*>(&S[(long)(t*256 + tid)*8]);
            float4 a = cp[0], b = cp[1];
            tile[0*256+tid]=a.x; tile[1*256+tid]=a.y; tile[2*256+tid]=a.z; tile[3*256+tid]=a.w;
            tile[4*256+tid]=b.x; tile[5*256+tid]=b.y; tile[6*256+tid]=b.z; tile[7*256+tid]=b.w;
            tile[8*256+tid]=SQ[t*256 + tid];
        }
        __syncthreads();

        float dot[QPW][4];
        #pragma unroll
        for (int qq=0;qq<QPW;++qq){ dot[qq][0]=0.f; dot[qq][1]=0.f; dot[qq][2]=0.f; dot[qq][3]=0.f; }
        #pragma unroll
        for (int k=0;k<8;++k){
            float4 v = *reinterpret_cast<const float4*>(&tile[k*256 + lane*4]);
            #pragma unroll
            for (int qq=0;qq<QPW;++qq){
                dot[qq][0] = fmaf(qa[qq][k], v.x, dot[qq][0]);
                dot[qq][1] = fmaf(qa[qq][k], v.y, dot[qq][1]);
                dot[qq][2] = fmaf(qa[qq][k], v.z, dot[qq][2]);
                dot[qq][3] = fmaf(qa[qq][k], v.w, dot[qq][3]);
            }
        }
        float4 sc = *reinterpret_cast<const float4*>(&tile[8*256 + lane*4]);
        const float scv[4] = {sc.x, sc.y, sc.z, sc.w};

        #pragma unroll
        for (int qq=0;qq<QPW;++qq){
            const int off = (q0+qq) - t*256;
            #pragma unroll
            for (int i=0;i<4;++i){
                float d2 = fmaf(-2.f, dot[qq][i], sqq[qq] + scv[i]);
                d2 = fmaxf(d2, 0.f);
                unsigned key = (__float_as_uint(d2) & 0xFFFFFF00u) | (unsigned)((t<<2)|i);
                if (lane*4 + i == off) key = 0xFFFFFFFFu;   // exclude self
                if (key < lmax[qq]) {
                    const bool a0 = (s0[qq] == lmax[qq]);
                    s0[qq] = a0 ? key : s0[qq];
                    s1[qq] = a0 ? s1[qq] : key;
                    lmax[qq] = s0[qq] > s1[qq] ? s0[qq] : s1[qq];
                }
            }
        }
    }

    // merge: per query, 40 extract-mins over 64 lanes x 2 slots
    #pragma unroll
    for (int qq=0; qq<QPW; ++qq) {
        const int q = q0 + qq;
        unsigned lmin = s0[qq] < s1[qq] ? s0[qq] : s1[qq];
        unsigned savedK = 0; int savedC = 0;
        #pragma unroll 1
        for (int p=0; p<KNN; ++p) {
            unsigned red = wave_umin64(lmin);
            unsigned gm = (unsigned)__builtin_amdgcn_readlane((int)red, 63);
            unsigned long long bal = __ballot(lmin == gm);
            int owner = __ffsll((long long)bal) - 1;
            if (lane == owner) {
                if (s0[qq] == gm) s0[qq] = 0xFFFFFFFFu; else s1[qq] = 0xFFFFFFFFu;
                lmin = s0[qq] < s1[qq] ? s0[qq] : s1[qq];
            }
            if (lane == p) { savedK = gm; savedC = owner; }
        }
        if (lane < KNN) {
            const int tl = (int)((savedK >> 2) & 0x3Fu);
            const int ii = (int)(savedK & 3u);
            const int c  = tl*256 + savedC*4 + ii;
            const float d2 = __uint_as_float(savedK & 0xFFFFFF00u);
            idx_out[(long)q*KNN + lane] = c;
            w_out[(long)q*KNN + lane]   = expf(-10.f * d2);
        }
    }
}

// ---------------- F2: GravNet aggregate + lin 56->64 ----------------
__global__ __launch_bounds__(256)
void f2_agg(const float* __restrict__ hg, const int* __restrict__ idx,
            const float* __restrict__ wgt, const float* __restrict__ x12g,
            const float* gWo, const float* gbo, float* __restrict__ xg)
{
    __shared__ int   IDs[64*40];
    __shared__ float Wt[64*40];
    __shared__ float AGG[64*57];
    __shared__ float Ws[56*64], Bs[64];
    const int tid = threadIdx.x;
    const long row0 = (long)blockIdx.x*64;
    for (int i=tid;i<64*40;i+=256){ int r=i/40,k=i-r*40;
        IDs[i]=idx[(row0+r)*40+k]; Wt[i]=wgt[(row0+r)*40+k]; }
    for (int i=tid;i<64*12;i+=256){ int r=i/12,c=i-r*12; AGG[r*57+44+c]=x12g[(row0+r)*12+c]; }
    __syncthreads();
    {
        const int r = tid & 63, g = tid >> 6;
        const int f0 = g*6;
        const int nf = (f0+6 <= 22) ? 6 : (22-f0);
        float sm[6], mx[6];
        #pragma unroll
        for (int u=0;u<6;++u){ sm[u]=0.f; mx[u]=-INFINITY; }
        #pragma unroll 1
        for (int k=0;k<40;++k){
            int j = IDs[r*40+k]; float wv = Wt[r*40+k];
            #pragma unroll
            for (int u=0;u<6;++u){
                if (u<nf){ float m = hg[(long)j*24+f0+u]*wv; sm[u]+=m; mx[u]=fmaxf(mx[u],m); }
            }
        }
        #pragma unroll
        for (int u=0;u<6;++u) if (u<nf){ AGG[r*57+f0+u]=sm[u]*(1.f/40.f); AGG[r*57+22+f0+u]=mx[u]; }
    }
    __syncthreads();
    lin_lds<56,64,false,256>(AGG,57, gWo,gbo, Ws,Bs, xg+row0*64,64, tid);
}

// ---------------- F3: GraphConv gather + dual linear ----------------
__global__ __launch_bounds__(256)
void f3_graphconv(const float* __restrict__ xgin, const int* __restrict__ idx,
                  const float* __restrict__ wgt,
                  const float* c2Wrel, const float* c2brel, const float* c2Wroot,
                  float* __restrict__ xc)
{
    __shared__ int   IDs[64*40];
    __shared__ float Wt[64*40];
    __shared__ float NB[64*65], XGs[64*65];
    __shared__ float Ws[64*64], Ws2[64*64], Bs[64];
    const int tid = threadIdx.x;
    const long row0 = (long)blockIdx.x*64;
    for (int i=tid;i<64*40;i+=256){ int r=i/40,k=i-r*40;
        IDs[i]=idx[(row0+r)*40+k]; Wt[i]=wgt[(row0+r)*40+k]; }
    for (int i=tid;i<64*64;i+=256){ int r=i>>6,c=i&63; XGs[r*65+c]=xgin[(row0+r)*64+c]; }
    __syncthreads();
    {
        const int r = tid & 63, g = tid >> 6;
        float acc[16];
        #pragma unroll
        for (int j=0;j<16;++j) acc[j]=0.f;
        #pragma unroll 1
        for (int k=0;k<40;++k){
            int j = IDs[r*40+k]; float wv = Wt[r*40+k];
            const float4* xp = reinterpret_cast<const float4*>(&xgin[(long)j*64 + g*16]);
            #pragma unroll
            for (int m=0;m<4;++m){
                float4 v = xp[m];
                acc[4*m+0]=fmaf(v.x,wv,acc[4*m+0]);
                acc[4*m+1]=fmaf(v.y,wv,acc[4*m+1]);
                acc[4*m+2]=fmaf(v.z,wv,acc[4*m+2]);
                acc[4*m+3]=fmaf(v.w,wv,acc[4*m+3]);
            }
        }
        #pragma unroll
        for (int j=0;j<16;++j) NB[r*65 + g*16 + j] = acc[j];
    }
    __syncthreads();
    lin_lds_dual<64,64,256>(NB,65, XGs,65, c2Wrel,c2brel,c2Wroot, Ws,Ws2,Bs, xc+row0*64,64, tid);
}

// ---------------- F4: nn2 head (4 layers) ----------------
__global__ __launch_bounds__(512)
void f4_nn2(const float* __restrict__ xc,
            const float* W0,const float* b0,const float* W1,const float* b1,
            const float* W2,const float* b2,const float* W3,const float* b3,
            float* __restrict__ out)
{
    __shared__ float A0[64*127], A1[64*127];
    __shared__ float Ws[126*128], Bs[128];
    const int tid = threadIdx.x;
    const long row0 = (long)blockIdx.x*64;
    for (int i=tid;i<64*64;i+=512){ int r=i>>6,c=i&63; A0[r*127+c]=xc[(row0+r)*64+c]; }
    lin_lds<64,126,true,512>(A0,127, W0,b0, Ws,Bs, A1,127, tid);
    lin_lds<126,126,true,512>(A1,127, W1,b1, Ws,Bs, A0,127, tid);
    lin_lds<126,126,true,512>(A0,127, W2,b2, Ws,Bs, A1,127, tid);
    lin_lds<126,6,true,512>(A1,127, W3,b3, Ws,Bs, out+row0*6,6, tid);
}

// ---------------- F5: nn3 head (concat + 4 layers) ----------------
__global__ __launch_bounds__(512)
void f5_nn3(const float* __restrict__ xc, const float* __restrict__ ids,
            const float* __restrict__ x0,
            const float* W0,const float* b0,const float* W1,const float* b1,
            const float* W2,const float* b2,const float* W3,const float* b3,
            float* __restrict__ out)
{
    __shared__ float A0[64*127], A1[64*127];
    __shared__ float Ws[126*128], Bs[128];
    const int tid = threadIdx.x;
    const long row0 = (long)blockIdx.x*64;
    for (int i=tid;i<64*64;i+=512){ int r=i>>6,c=i&63; A0[r*127+c]=xc[(row0+r)*64+c]; }
    for (int i=tid;i<64*6;i+=512){ int r=i/6,c=i-r*6; A0[r*127+64+c]=ids[(row0+r)*6+c]; }
    for (int i=tid;i<64*12;i+=512){ int r=i/12,c=i-r*12; A0[r*127+70+c]=x0[(row0+r)*12+c]; }
    lin_lds<82,126,true,512>(A0,127, W0,b0, Ws,Bs, A1,127, tid);
    lin_lds<126,126,true,512>(A1,127, W1,b1, Ws,Bs, A0,127, tid);
    lin_lds<126,126,true,512>(A0,127, W2,b2, Ws,Bs, A1,127, tid);
    lin_lds<126,6,true,512>(A1,127, W3,b3, Ws,Bs, out+row0*6,6, tid);
}

// ---------------- passthrough outputs ----------------
__global__ void copyout_kernel(const int* __restrict__ gid, const float* __restrict__ gy,
                               const int* __restrict__ cid, const float* __restrict__ cy,
                               float* __restrict__ out, int N)
{
    long i = (long)blockIdx.x*blockDim.x + threadIdx.x;
    long n = N;
    if (i < n)            out[12*n + i]         = (float)gid[i];
    else if (i < 7*n)     out[13*n + (i - n)]   = gy[i - n];
    else if (i < 8*n)     out[19*n + (i - 7*n)] = (float)cid[i - 7*n];
    else if (i < 14*n)    out[20*n + (i - 8*n)] = cy[i - 8*n];
}

extern "C" void kernel_launch(void* const* d_in, const int* in_sizes, int n_in,
                              void* d_out, int out_size, void* d_ws, size_t ws_size,
                              hipStream_t stream)
{
    const float* x0     = (const float*)d_in[0];
    const float* ygen   = (const float*)d_in[1];
    const float* ycand  = (const float*)d_in[2];
    const int*   ygenid = (const int*)d_in[3];
    const int*   ycandid= (const int*)d_in[4];
    const float* n1W0=(const float*)d_in[5],  *n1b0=(const float*)d_in[6];
    const float* n1W1=(const float*)d_in[7],  *n1b1=(const float*)d_in[8];
    const float* n1W2=(const float*)d_in[9],  *n1b2=(const float*)d_in[10];
    const float* gWs =(const float*)d_in[11], *gbs =(const float*)d_in[12];
    const float* gWh =(const float*)d_in[13], *gbh =(const float*)d_in[14];
    const float* gWo =(const float*)d_in[15], *gbo =(const float*)d_in[16];
    const float* c2Wrel=(const float*)d_in[17], *c2brel=(const float*)d_in[18];
    const float* c2Wroot=(const float*)d_in[19];
    const float* n2W0=(const float*)d_in[20], *n2b0=(const float*)d_in[21];
    const float* n2W1=(const float*)d_in[22], *n2b1=(const float*)d_in[23];
    const float* n2W2=(const float*)d_in[24], *n2b2=(const float*)d_in[25];
    const float* n2W3=(const float*)d_in[26], *n2b3=(const float*)d_in[27];
    const float* n3W0=(const float*)d_in[28], *n3b0=(const float*)d_in[29];
    const float* n3W1=(const float*)d_in[30], *n3b1=(const float*)d_in[31];
    const float* n3W2=(const float*)d_in[32], *n3b2=(const float*)d_in[33];
    const float* n3W3=(const float*)d_in[34], *n3b3=(const float*)d_in[35];

    const int N = in_sizes[0] / 12;      // 16384
    float* ws = (float*)d_ws;
    size_t off = 0;
    auto alloc = [&](size_t cnt){ float* p = ws + off; off += cnt; return p; };
    float* x12  = alloc((size_t)N*12);
    float* s    = alloc((size_t)N*8);
    float* sq   = alloc((size_t)N);
    float* h    = alloc((size_t)N*24);
    int*   idxb = (int*)alloc((size_t)N*KNN);
    float* wb   = alloc((size_t)N*KNN);
    float* xg   = alloc((size_t)N*64);
    float* xc   = alloc((size_t)N*64);
    (void)ws_size; (void)n_in; (void)out_size;

    float* outF = (float*)d_out;
    const int GB = N / 64;               // 256 blocks

    f1_encoder<<<GB,256,0,stream>>>(x0, n1W0,n1b0, n1W1,n1b1, n1W2,n1b2,
                                    gWs,gbs, gWh,gbh, x12, s, sq, h);
    knn_kernel<<<N/(KNN_WPB*QPW), 256, 0, stream>>>(s, sq, idxb, wb, N);
    f2_agg<<<GB,256,0,stream>>>(h, idxb, wb, x12, gWo, gbo, xg);
    f3_graphconv<<<GB,256,0,stream>>>(xg, idxb, wb, c2Wrel, c2brel, c2Wroot, xc);
    f4_nn2<<<GB,512,0,stream>>>(xc, n2W0,n2b0, n2W1,n2b1, n2W2,n2b2, n2W3,n2b3, outF);
    f5_nn3<<<GB,512,0,stream>>>(xc, outF, x0, n3W0,n3b0, n3W1,n3b1, n3W2,n3b2, n3W3,n3b3,
                                outF + (size_t)N*6);
    copyout_kernel<<<(14*N+255)/256,256,0,stream>>>(ygenid, ygen, ycandid, ycand, outF, N);
}

// Round 6
// 312.585 us; speedup vs baseline: 10.8523x; 1.1501x over previous
//
#include <hip/hip_runtime.h>
#include <math.h>

static constexpr int KNN = 40;

__device__ __forceinline__ float lrelu_f(float v){ return v >= 0.f ? v : 0.5f*v; }

#define FMA16(xv, wbase) do{ const float4* wp_ = reinterpret_cast<const float4*>(wbase); \
  float4 w0_=wp_[0],w1_=wp_[1],w2_=wp_[2],w3_=wp_[3]; \
  acc[0]=fmaf(xv,w0_.x,acc[0]); acc[1]=fmaf(xv,w0_.y,acc[1]); acc[2]=fmaf(xv,w0_.z,acc[2]); acc[3]=fmaf(xv,w0_.w,acc[3]); \
  acc[4]=fmaf(xv,w1_.x,acc[4]); acc[5]=fmaf(xv,w1_.y,acc[5]); acc[6]=fmaf(xv,w1_.z,acc[6]); acc[7]=fmaf(xv,w1_.w,acc[7]); \
  acc[8]=fmaf(xv,w2_.x,acc[8]); acc[9]=fmaf(xv,w2_.y,acc[9]); acc[10]=fmaf(xv,w2_.z,acc[10]); acc[11]=fmaf(xv,w2_.w,acc[11]); \
  acc[12]=fmaf(xv,w3_.x,acc[12]); acc[13]=fmaf(xv,w3_.y,acc[13]); acc[14]=fmaf(xv,w3_.z,acc[14]); acc[15]=fmaf(xv,w3_.w,acc[15]); }while(0)

// ---- in-block linear stage: Y(r,c) = act( Xs(r,:) @ W + b ), 64 rows per block ----
template<int K, int NOUT, bool RELU, int NTH>
__device__ __forceinline__
void lin_lds(const float* __restrict__ Xs, int xpitch,
             const float* __restrict__ W, const float* __restrict__ Bv,
             float* __restrict__ Ws, float* __restrict__ Bs,
             float* __restrict__ Y, int ypitch, int tid)
{
    constexpr int NP  = ((NOUT+15)/16)*16;
    constexpr int CGS = NP/16;
    for (int i = tid; i < K*NP; i += NTH) {
        int k = i / NP, c = i - k*NP;
        Ws[i] = (c < NOUT) ? W[k*NOUT + c] : 0.f;
    }
    for (int i = tid; i < NP; i += NTH) Bs[i] = (i < NOUT) ? Bv[i] : 0.f;
    __syncthreads();
    const int r = tid & 63;
    for (int cg = tid >> 6; cg < CGS; cg += (NTH >> 6)) {
        float acc[16];
        #pragma unroll
        for (int j=0;j<16;++j) acc[j] = Bs[cg*16+j];
        const float* xrow = &Xs[(long)r*xpitch];
        #pragma unroll 4
        for (int k=0;k<K;++k) { const float xv = xrow[k]; FMA16(xv, &Ws[k*NP + cg*16]); }
        #pragma unroll
        for (int j=0;j<16;++j) {
            int c = cg*16 + j;
            if (c < NOUT) { float v = acc[j]; if (RELU) v = lrelu_f(v); Y[(long)r*ypitch + c] = v; }
        }
    }
    __syncthreads();
}

// dual: Y = Xs@W + b + X2s@W2 (no activation)
template<int K, int NOUT, int NTH>
__device__ __forceinline__
void lin_lds_dual(const float* __restrict__ Xs, int xp, const float* __restrict__ X2s, int xp2,
                  const float* __restrict__ W, const float* __restrict__ Bv, const float* __restrict__ W2,
                  float* __restrict__ Ws, float* __restrict__ Ws2, float* __restrict__ Bs,
                  float* __restrict__ Y, int ypitch, int tid)
{
    constexpr int NP  = ((NOUT+15)/16)*16;
    constexpr int CGS = NP/16;
    for (int i = tid; i < K*NP; i += NTH) {
        int k = i / NP, c = i - k*NP;
        Ws[i]  = (c < NOUT) ? W[k*NOUT + c]  : 0.f;
        Ws2[i] = (c < NOUT) ? W2[k*NOUT + c] : 0.f;
    }
    for (int i = tid; i < NP; i += NTH) Bs[i] = (i < NOUT) ? Bv[i] : 0.f;
    __syncthreads();
    const int r = tid & 63;
    for (int cg = tid >> 6; cg < CGS; cg += (NTH >> 6)) {
        float acc[16];
        #pragma unroll
        for (int j=0;j<16;++j) acc[j] = Bs[cg*16+j];
        {
            const float* xrow = &Xs[(long)r*xp];
            #pragma unroll 4
            for (int k=0;k<K;++k) { const float xv = xrow[k]; FMA16(xv, &Ws[k*NP + cg*16]); }
        }
        {
            const float* xrow = &X2s[(long)r*xp2];
            #pragma unroll 4
            for (int k=0;k<K;++k) { const float xv = xrow[k]; FMA16(xv, &Ws2[k*NP + cg*16]); }
        }
        #pragma unroll
        for (int j=0;j<16;++j) {
            int c = cg*16 + j;
            if (c < NOUT) Y[(long)r*ypitch + c] = acc[j];
        }
    }
    __syncthreads();
}

// ---------------- F1: nn1 encoder + gWs + gWh + |s|^2 ----------------
__global__ __launch_bounds__(256)
void f1_encoder(const float* __restrict__ x0,
                const float* n1W0,const float* n1b0,const float* n1W1,const float* n1b1,
                const float* n1W2,const float* n1b2,
                const float* gWs,const float* gbs,const float* gWh,const float* gbh,
                float* __restrict__ x12g, float* __restrict__ sg,
                float* __restrict__ sqg, float* __restrict__ hg /*pitch 32*/)
{
    __shared__ float A1[64*65], A2[64*65], Ss[64*9];
    __shared__ float Ws[64*128], Bs[128];
    const int tid = threadIdx.x;
    const long row0 = (long)blockIdx.x*64;
    lin_lds<12,64,true,256>(x0+row0*12,12, n1W0,n1b0, Ws,Bs, A1,65, tid);
    lin_lds<64,64,true,256>(A1,65, n1W1,n1b1, Ws,Bs, A2,65, tid);
    lin_lds<64,12,true,256>(A2,65, n1W2,n1b2, Ws,Bs, A1,13, tid);
    for (int i=tid;i<64*12;i+=256){ int r=i/12,c=i-r*12; x12g[(row0+r)*12+c]=A1[r*13+c]; }
    lin_lds<12,8,false,256>(A1,13, gWs,gbs, Ws,Bs, Ss,9, tid);
    lin_lds<12,22,false,256>(A1,13, gWh,gbh, Ws,Bs, hg+row0*32,32, tid);
    if (tid < 64) {
        float acc = 0.f;
        #pragma unroll
        for (int k=0;k<8;++k){ float v=Ss[tid*9+k]; sg[(row0+tid)*8+k]=v; acc=fmaf(v,v,acc); }
        sqg[row0+tid] = acc;
    }
}

// ---------------- kNN: 4 q/wave, 4 cand/lane, sorted-pair top-2, DPP merge ----------------
template<int C>
__device__ __forceinline__ unsigned dpp_umin(unsigned x){
    unsigned y = (unsigned)__builtin_amdgcn_update_dpp((int)x, (int)x, C, 0xf, 0xf, false);
    return x < y ? x : y;
}
__device__ __forceinline__ unsigned wave_umin64(unsigned x){
    x = dpp_umin<0x111>(x);
    x = dpp_umin<0x112>(x);
    x = dpp_umin<0x114>(x);
    x = dpp_umin<0x118>(x);
    x = dpp_umin<0x142>(x);
    x = dpp_umin<0x143>(x);
    return x;   // lane 63 holds the wave min
}

#define KNN_WPB 4
#define QPW 4

__global__ __launch_bounds__(256)
void knn_kernel(const float* __restrict__ S, const float* __restrict__ SQ,
                int* __restrict__ idx_out, float* __restrict__ w_out, int N)
{
    __shared__ __align__(16) float tile[9*256];
    const int tid  = threadIdx.x;
    const int lane = tid & 63;
    const int wv   = tid >> 6;
    const int q0   = (blockIdx.x*KNN_WPB + wv)*QPW;
    const int qtile = q0 >> 8;   // the one tile containing this wave's queries

    float qa[QPW][8]; float sqq[QPW];
    #pragma unroll
    for (int qq=0; qq<QPW; ++qq) {
        const float4* qp = reinterpret_cast<const float4*>(&S[(long)(q0+qq)*8]);
        float4 a = qp[0], b = qp[1];
        qa[qq][0]=a.x; qa[qq][1]=a.y; qa[qq][2]=a.z; qa[qq][3]=a.w;
        qa[qq][4]=b.x; qa[qq][5]=b.y; qa[qq][6]=b.z; qa[qq][7]=b.w;
        sqq[qq] = SQ[q0+qq];
    }

    // sorted pair: s0 <= s1, the two smallest keys seen by this lane
    unsigned s0[QPW], s1[QPW];
    #pragma unroll
    for (int qq=0; qq<QPW; ++qq){ s0[qq]=0xFFFFFFFFu; s1[qq]=0xFFFFFFFFu; }

    const int NT = N >> 8;
    #pragma unroll 1
    for (int t = 0; t < NT; ++t) {
        __syncthreads();
        {
            const float4* cp = reinterpret_cast<const float4*>(&S[(long)(t*256 + tid)*8]);
            float4 a = cp[0], b = cp[1];
            tile[0*256+tid]=a.x; tile[1*256+tid]=a.y; tile[2*256+tid]=a.z; tile[3*256+tid]=a.w;
            tile[4*256+tid]=b.x; tile[5*256+tid]=b.y; tile[6*256+tid]=b.z; tile[7*256+tid]=b.w;
            tile[8*256+tid]=SQ[t*256 + tid];
        }
        __syncthreads();

        float dot[QPW][4];
        #pragma unroll
        for (int qq=0;qq<QPW;++qq){ dot[qq][0]=0.f; dot[qq][1]=0.f; dot[qq][2]=0.f; dot[qq][3]=0.f; }
        #pragma unroll
        for (int k=0;k<8;++k){
            float4 v = *reinterpret_cast<const float4*>(&tile[k*256 + lane*4]);
            #pragma unroll
            for (int qq=0;qq<QPW;++qq){
                dot[qq][0] = fmaf(qa[qq][k], v.x, dot[qq][0]);
                dot[qq][1] = fmaf(qa[qq][k], v.y, dot[qq][1]);
                dot[qq][2] = fmaf(qa[qq][k], v.z, dot[qq][2]);
                dot[qq][3] = fmaf(qa[qq][k], v.w, dot[qq][3]);
            }
        }
        float4 sc = *reinterpret_cast<const float4*>(&tile[8*256 + lane*4]);
        const float scv[4] = {sc.x, sc.y, sc.z, sc.w};

        if (t != qtile) {
            #pragma unroll
            for (int qq=0;qq<QPW;++qq){
                #pragma unroll
                for (int i=0;i<4;++i){
                    float d2 = fmaf(-2.f, dot[qq][i], sqq[qq] + scv[i]);
                    d2 = fmaxf(d2, 0.f);
                    unsigned key = (__float_as_uint(d2) & 0xFFFFFF00u) | (unsigned)((t<<2)|i);
                    unsigned lo = s0[qq] < key ? s0[qq] : key;      // min
                    unsigned hi = s0[qq] > key ? s0[qq] : key;      // max
                    s0[qq] = lo;
                    s1[qq] = s1[qq] < hi ? s1[qq] : hi;             // min
                }
            }
        } else {
            #pragma unroll
            for (int qq=0;qq<QPW;++qq){
                const int off = (q0+qq) - t*256;
                #pragma unroll
                for (int i=0;i<4;++i){
                    float d2 = fmaf(-2.f, dot[qq][i], sqq[qq] + scv[i]);
                    d2 = fmaxf(d2, 0.f);
                    unsigned key = (__float_as_uint(d2) & 0xFFFFFF00u) | (unsigned)((t<<2)|i);
                    if (lane*4 + i == off) key = 0xFFFFFFFFu;   // exclude self
                    unsigned lo = s0[qq] < key ? s0[qq] : key;
                    unsigned hi = s0[qq] > key ? s0[qq] : key;
                    s0[qq] = lo;
                    s1[qq] = s1[qq] < hi ? s1[qq] : hi;
                }
            }
        }
    }

    // merge: per query, 40 extract-mins over 64 lanes x sorted pair
    #pragma unroll
    for (int qq=0; qq<QPW; ++qq) {
        const int q = q0 + qq;
        unsigned savedK = 0; int savedC = 0;
        #pragma unroll 1
        for (int p=0; p<KNN; ++p) {
            unsigned red = wave_umin64(s0[qq]);
            unsigned gm = (unsigned)__builtin_amdgcn_readlane((int)red, 63);
            unsigned long long bal = __ballot(s0[qq] == gm);
            int owner = __ffsll((long long)bal) - 1;
            if (lane == owner) { s0[qq] = s1[qq]; s1[qq] = 0xFFFFFFFFu; }
            if (lane == p) { savedK = gm; savedC = owner; }
        }
        if (lane < KNN) {
            const int tl = (int)((savedK >> 2) & 0x3Fu);
            const int ii = (int)(savedK & 3u);
            const int c  = tl*256 + savedC*4 + ii;
            const float d2 = __uint_as_float(savedK & 0xFFFFFF00u);
            idx_out[(long)q*KNN + lane] = c;
            w_out[(long)q*KNN + lane]   = expf(-10.f * d2);
        }
    }
}

// ---------------- F2: GravNet aggregate + lin 56->64 ----------------
__global__ __launch_bounds__(256)
void f2_agg(const float* __restrict__ hg /*pitch 32*/, const int* __restrict__ idx,
            const float* __restrict__ wgt, const float* __restrict__ x12g,
            const float* gWo, const float* gbo, float* __restrict__ xg)
{
    __shared__ int   IDs[64*40];
    __shared__ float Wt[64*40];
    __shared__ float AGG[64*57];
    __shared__ float Ws[56*64], Bs[64];
    const int tid = threadIdx.x;
    const long row0 = (long)blockIdx.x*64;
    for (int i=tid;i<64*40;i+=256){ int r=i/40,k=i-r*40;
        IDs[i]=idx[(row0+r)*40+k]; Wt[i]=wgt[(row0+r)*40+k]; }
    for (int i=tid;i<64*12;i+=256){ int r=i/12,c=i-r*12; AGG[r*57+44+c]=x12g[(row0+r)*12+c]; }
    __syncthreads();
    {
        const int r = tid & 63, g = tid >> 6;   // g in 0..3, feats f0 = g*8 (g=3 idle)
        const int f0 = g*8;
        const int nf = (f0 < 22) ? ((22-f0) < 8 ? (22-f0) : 8) : 0;
        float sm[8], mx[8];
        #pragma unroll
        for (int u=0;u<8;++u){ sm[u]=0.f; mx[u]=-INFINITY; }
        if (nf > 0) {
            #pragma unroll 1
            for (int k=0;k<40;++k){
                int j = IDs[r*40+k]; float wv = Wt[r*40+k];
                const float4* hp = reinterpret_cast<const float4*>(&hg[(long)j*32 + f0]);
                float4 h0 = hp[0], h1 = hp[1];
                float hv[8] = {h0.x,h0.y,h0.z,h0.w, h1.x,h1.y,h1.z,h1.w};
                #pragma unroll
                for (int u=0;u<8;++u){ float m = hv[u]*wv; sm[u]+=m; mx[u]=fmaxf(mx[u],m); }
            }
            #pragma unroll
            for (int u=0;u<8;++u) if (u<nf){ AGG[r*57+f0+u]=sm[u]*(1.f/40.f); AGG[r*57+22+f0+u]=mx[u]; }
        }
    }
    __syncthreads();
    lin_lds<56,64,false,256>(AGG,57, gWo,gbo, Ws,Bs, xg+row0*64,64, tid);
}

// ---------------- F3: GraphConv gather + dual linear ----------------
__global__ __launch_bounds__(256)
void f3_graphconv(const float* __restrict__ xgin, const int* __restrict__ idx,
                  const float* __restrict__ wgt,
                  const float* c2Wrel, const float* c2brel, const float* c2Wroot,
                  float* __restrict__ xc)
{
    __shared__ int   IDs[64*40];
    __shared__ float Wt[64*40];
    __shared__ float NB[64*65], XGs[64*65];
    __shared__ float Ws[64*64], Ws2[64*64], Bs[64];
    const int tid = threadIdx.x;
    const long row0 = (long)blockIdx.x*64;
    for (int i=tid;i<64*40;i+=256){ int r=i/40,k=i-r*40;
        IDs[i]=idx[(row0+r)*40+k]; Wt[i]=wgt[(row0+r)*40+k]; }
    for (int i=tid;i<64*64;i+=256){ int r=i>>6,c=i&63; XGs[r*65+c]=xgin[(row0+r)*64+c]; }
    __syncthreads();
    {
        const int r = tid & 63, g = tid >> 6;
        float acc[16];
        #pragma unroll
        for (int j=0;j<16;++j) acc[j]=0.f;
        #pragma unroll 1
        for (int k=0;k<40;++k){
            int j = IDs[r*40+k]; float wv = Wt[r*40+k];
            const float4* xp = reinterpret_cast<const float4*>(&xgin[(long)j*64 + g*16]);
            #pragma unroll
            for (int m=0;m<4;++m){
                float4 v = xp[m];
                acc[4*m+0]=fmaf(v.x,wv,acc[4*m+0]);
                acc[4*m+1]=fmaf(v.y,wv,acc[4*m+1]);
                acc[4*m+2]=fmaf(v.z,wv,acc[4*m+2]);
                acc[4*m+3]=fmaf(v.w,wv,acc[4*m+3]);
            }
        }
        #pragma unroll
        for (int j=0;j<16;++j) NB[r*65 + g*16 + j] = acc[j];
    }
    __syncthreads();
    lin_lds_dual<64,64,256>(NB,65, XGs,65, c2Wrel,c2brel,c2Wroot, Ws,Ws2,Bs, xc+row0*64,64, tid);
}

// ---------------- F45: nn2 head + concat + nn3 head ----------------
__global__ __launch_bounds__(512)
void f45_heads(const float* __restrict__ xc, const float* __restrict__ x0,
               const float* A_W0,const float* A_b0,const float* A_W1,const float* A_b1,
               const float* A_W2,const float* A_b2,const float* A_W3,const float* A_b3,
               const float* B_W0,const float* B_b0,const float* B_W1,const float* B_b1,
               const float* B_W2,const float* B_b2,const float* B_W3,const float* B_b3,
               float* __restrict__ outIds, float* __restrict__ outP4)
{
    __shared__ float A0[64*127], A1[64*127], IDS[64*6];
    __shared__ float Ws[126*128], Bs[128];
    const int tid = threadIdx.x;
    const long row0 = (long)blockIdx.x*64;
    // ---- nn2 ----
    for (int i=tid;i<64*64;i+=512){ int r=i>>6,c=i&63; A0[r*127+c]=xc[(row0+r)*64+c]; }
    lin_lds<64,126,true,512>(A0,127, A_W0,A_b0, Ws,Bs, A1,127, tid);
    lin_lds<126,126,true,512>(A1,127, A_W1,A_b1, Ws,Bs, A0,127, tid);
    lin_lds<126,126,true,512>(A0,127, A_W2,A_b2, Ws,Bs, A1,127, tid);
    lin_lds<126,6,true,512>(A1,127, A_W3,A_b3, Ws,Bs, IDS,6, tid);
    __syncthreads();
    for (int i=tid;i<64*6;i+=512){ int r=i/6,c=i-r*6; outIds[(row0+r)*6+c]=IDS[i]; }
    // ---- concat [xc, ids, x0] -> 82 ----
    for (int i=tid;i<64*64;i+=512){ int r=i>>6,c=i&63; A0[r*127+c]=xc[(row0+r)*64+c]; }
    for (int i=tid;i<64*6;i+=512){ int r=i/6,c=i-r*6; A0[r*127+64+c]=IDS[i]; }
    for (int i=tid;i<64*12;i+=512){ int r=i/12,c=i-r*12; A0[r*127+70+c]=x0[(row0+r)*12+c]; }
    __syncthreads();
    // ---- nn3 ----
    lin_lds<82,126,true,512>(A0,127, B_W0,B_b0, Ws,Bs, A1,127, tid);
    lin_lds<126,126,true,512>(A1,127, B_W1,B_b1, Ws,Bs, A0,127, tid);
    lin_lds<126,126,true,512>(A0,127, B_W2,B_b2, Ws,Bs, A1,127, tid);
    lin_lds<126,6,true,512>(A1,127, B_W3,B_b3, Ws,Bs, outP4+row0*6,6, tid);
}

// ---------------- passthrough outputs ----------------
__global__ void copyout_kernel(const int* __restrict__ gid, const float* __restrict__ gy,
                               const int* __restrict__ cid, const float* __restrict__ cy,
                               float* __restrict__ out, int N)
{
    long i = (long)blockIdx.x*blockDim.x + threadIdx.x;
    long n = N;
    if (i < n)            out[12*n + i]         = (float)gid[i];
    else if (i < 7*n)     out[13*n + (i - n)]   = gy[i - n];
    else if (i < 8*n)     out[19*n + (i - 7*n)] = (float)cid[i - 7*n];
    else if (i < 14*n)    out[20*n + (i - 8*n)] = cy[i - 8*n];
}

extern "C" void kernel_launch(void* const* d_in, const int* in_sizes, int n_in,
                              void* d_out, int out_size, void* d_ws, size_t ws_size,
                              hipStream_t stream)
{
    const float* x0     = (const float*)d_in[0];
    const float* ygen   = (const float*)d_in[1];
    const float* ycand  = (const float*)d_in[2];
    const int*   ygenid = (const int*)d_in[3];
    const int*   ycandid= (const int*)d_in[4];
    const float* n1W0=(const float*)d_in[5],  *n1b0=(const float*)d_in[6];
    const float* n1W1=(const float*)d_in[7],  *n1b1=(const float*)d_in[8];
    const float* n1W2=(const float*)d_in[9],  *n1b2=(const float*)d_in[10];
    const float* gWs =(const float*)d_in[11], *gbs =(const float*)d_in[12];
    const float* gWh =(const float*)d_in[13], *gbh =(const float*)d_in[14];
    const float* gWo =(const float*)d_in[15], *gbo =(const float*)d_in[16];
    const float* c2Wrel=(const float*)d_in[17], *c2brel=(const float*)d_in[18];
    const float* c2Wroot=(const float*)d_in[19];
    const float* n2W0=(const float*)d_in[20], *n2b0=(const float*)d_in[21];
    const float* n2W1=(const float*)d_in[22], *n2b1=(const float*)d_in[23];
    const float* n2W2=(const float*)d_in[24], *n2b2=(const float*)d_in[25];
    const float* n2W3=(const float*)d_in[26], *n2b3=(const float*)d_in[27];
    const float* n3W0=(const float*)d_in[28], *n3b0=(const float*)d_in[29];
    const float* n3W1=(const float*)d_in[30], *n3b1=(const float*)d_in[31];
    const float* n3W2=(const float*)d_in[32], *n3b2=(const float*)d_in[33];
    const float* n3W3=(const float*)d_in[34], *n3b3=(const float*)d_in[35];

    const int N = in_sizes[0] / 12;      // 16384
    float* ws = (float*)d_ws;
    size_t off = 0;
    auto alloc = [&](size_t cnt){ float* p = ws + off; off += cnt; return p; };
    float* x12  = alloc((size_t)N*12);
    float* s    = alloc((size_t)N*8);
    float* sq   = alloc((size_t)N);
    float* h    = alloc((size_t)N*32);
    int*   idxb = (int*)alloc((size_t)N*KNN);
    float* wb   = alloc((size_t)N*KNN);
    float* xg   = alloc((size_t)N*64);
    float* xc   = alloc((size_t)N*64);
    (void)ws_size; (void)n_in; (void)out_size;

    float* outF = (float*)d_out;
    const int GB = N / 64;               // 256 blocks

    f1_encoder<<<GB,256,0,stream>>>(x0, n1W0,n1b0, n1W1,n1b1, n1W2,n1b2,
                                    gWs,gbs, gWh,gbh, x12, s, sq, h);
    knn_kernel<<<N/(KNN_WPB*QPW), 256, 0, stream>>>(s, sq, idxb, wb, N);
    f2_agg<<<GB,256,0,stream>>>(h, idxb, wb, x12, gWo, gbo, xg);
    f3_graphconv<<<GB,256,0,stream>>>(xg, idxb, wb, c2Wrel, c2brel, c2Wroot, xc);
    f45_heads<<<GB,512,0,stream>>>(xc, x0,
                                   n2W0,n2b0, n2W1,n2b1, n2W2,n2b2, n2W3,n2b3,
                                   n3W0,n3b0, n3W1,n3b1, n3W2,n3b2, n3W3,n3b3,
                                   outF, outF + (size_t)N*6);
    copyout_kernel<<<(14*N+255)/256,256,0,stream>>>(ygenid, ygen, ycandid, ycand, outF, N);
}